// Round 6
// baseline (328.689 us; speedup 1.0000x reference)
//
#include <hip/hip_runtime.h>
#include <stdint.h>

// Problem constants (B=4096, D=1024 from setup_inputs)
#define BSZ 4096
#define DIM 1024
#define EPSV 1e-6f
#define MARGINV 0.3f
#define SROWS 4

// ---------------- Threefry-2x32 (bit-exact vs JAX lowering) ----------------
#define TF_ROT(x0, x1, r) { x0 += x1; x1 = ((x1 << r) | (x1 >> (32 - r))); x1 ^= x0; }

__host__ __device__ __forceinline__ void threefry2x32(uint32_t k0, uint32_t k1,
                                                      uint32_t c0, uint32_t c1,
                                                      uint32_t& o0, uint32_t& o1) {
  uint32_t ks2 = k0 ^ k1 ^ 0x1BD11BDAu;
  uint32_t x0 = c0 + k0;
  uint32_t x1 = c1 + k1;
  TF_ROT(x0, x1, 13) TF_ROT(x0, x1, 15) TF_ROT(x0, x1, 26) TF_ROT(x0, x1, 6)
  x0 += k1;  x1 += ks2 + 1u;
  TF_ROT(x0, x1, 17) TF_ROT(x0, x1, 29) TF_ROT(x0, x1, 16) TF_ROT(x0, x1, 24)
  x0 += ks2; x1 += k0 + 2u;
  TF_ROT(x0, x1, 13) TF_ROT(x0, x1, 15) TF_ROT(x0, x1, 26) TF_ROT(x0, x1, 6)
  x0 += k0;  x1 += k1 + 3u;
  TF_ROT(x0, x1, 17) TF_ROT(x0, x1, 29) TF_ROT(x0, x1, 16) TF_ROT(x0, x1, 24)
  x0 += k1;  x1 += ks2 + 4u;
  TF_ROT(x0, x1, 13) TF_ROT(x0, x1, 15) TF_ROT(x0, x1, 26) TF_ROT(x0, x1, 6)
  x0 += ks2; x1 += k0 + 5u;
  o0 = x0; o1 = x1;
}

__device__ __forceinline__ uint16_t f2bf(float f) {  // RNE float->bf16
  uint32_t u = __float_as_uint(f);
  u += 0x7FFFu + ((u >> 16) & 1u);
  return (uint16_t)(u >> 16);
}

// ---------------- Kernel 1: norms/sums/nv + fp8 convert + zero ticket ----------------
__global__ __launch_bounds__(256) void prep_kernel(const float* __restrict__ F,
                                                   uint8_t* __restrict__ Fq,
                                                   float* __restrict__ norm2,
                                                   float* __restrict__ sums,
                                                   float* __restrict__ nv,
                                                   unsigned int* __restrict__ ticket) {
  const int w = threadIdx.x >> 6, l = threadIdx.x & 63;
  const int r = blockIdx.x * 4 + w;  // one wave per row
  const float4* src = (const float4*)(F + (size_t)r * DIM);
  uint32_t* dst = (uint32_t*)(Fq + (size_t)r * DIM);
  float s = 0.f, q = 0.f;
#pragma unroll
  for (int c = 0; c < 4; ++c) {
    float4 v = src[c * 64 + l];
    s += (v.x + v.y) + (v.z + v.w);
    q += v.x * v.x + v.y * v.y + v.z * v.z + v.w * v.w;
    int wd = 0;
    wd = __builtin_amdgcn_cvt_pk_fp8_f32(v.x, v.y, wd, false);  // bytes 0,1
    wd = __builtin_amdgcn_cvt_pk_fp8_f32(v.z, v.w, wd, true);   // bytes 2,3
    dst[c * 64 + l] = (uint32_t)wd;
  }
  for (int off = 32; off; off >>= 1) { s += __shfl_xor(s, off); q += __shfl_xor(q, off); }
  if (l == 0) {
    norm2[r] = q; sums[r] = s;
    nv[r] = q + 2.0f * EPSV * s;
  }
  if (blockIdx.x == 0 && threadIdx.x == 0) ticket[0] = 0u;
}

// ---------------- Kernel 2: triplet mining, 4 rows/block (labels amortized) ----------------
// NEG: one threefry per pair, 32-bit lane-local argmax key (mant<<4)|(15-c)
//      (tie -> lower c = lower j within lane); cross-lane via 64-bit (mant<<32)|~j.
// POS: same-label js pushed to LDS list during neg scan (~8/row), wave-per-row phase 2.
__global__ __launch_bounds__(256) void sample_kernel(const int* __restrict__ labels,
                                                     int* __restrict__ pos_idx,
                                                     int* __restrict__ neg_idx,
                                                     uint32_t p0, uint32_t p1,
                                                     uint32_t n0, uint32_t n1) {
  __shared__ int plist[SROWS][64];
  __shared__ int pcnt[SROWS];
  __shared__ unsigned long long swp[SROWS];
  __shared__ unsigned long long swn[SROWS];
  const int t = threadIdx.x;
  const int i0 = blockIdx.x * SROWS;
  if (t < SROWS) { pcnt[t] = 0; swp[t] = 0ull; swn[t] = 0ull; }
  int lj[16];
#pragma unroll
  for (int c = 0; c < 16; ++c) lj[c] = labels[c * 256 + t];
  __syncthreads();
  const int lane = t & 63;
  for (int r = 0; r < SROWS; ++r) {
    const int li = labels[i0 + r];  // block-uniform -> scalar load
    const uint32_t base = (uint32_t)(i0 + r) * (uint32_t)BSZ + (uint32_t)t;
    uint32_t bestn = 0u;
#pragma unroll
    for (int c = 0; c < 16; ++c) {
      uint32_t y0, y1;
      threefry2x32(n0, n1, 0u, base + (uint32_t)(c * 256), y0, y1);
      const uint32_t pack = (((y0 ^ y1) >> 9) << 4) | (uint32_t)(15 - c);
      const bool eq = (lj[c] == li);
      if (eq) {  // rare: ~8 lanes per row
        int sl = atomicAdd(&pcnt[r], 1);
        if (sl < 64) plist[r][sl] = c * 256 + t;
      }
      const uint32_t v = eq ? 0u : pack;
      if (v > bestn) bestn = v;
    }
    // lane-local 32-bit -> global 64-bit key
    unsigned long long keyn = 0ull;
    if (bestn) {
      const int c = 15 - (int)(bestn & 15u);
      const int j = c * 256 + t;
      keyn = ((unsigned long long)(bestn >> 4) << 32) | (uint32_t)(~j);
    }
    for (int off = 32; off; off >>= 1) {
      unsigned long long o = __shfl_xor(keyn, off);
      if (o > keyn) keyn = o;
    }
    if (lane == 0) atomicMax(&swn[r], keyn);
  }
  __syncthreads();  // fences plist/pcnt/swn
  // POS phase: wave w handles row w's candidate list
  const int w = t >> 6;
  {
    const int cnt = pcnt[w] < 64 ? pcnt[w] : 64;
    if (lane < cnt) {
      const int j = plist[w][lane];
      uint32_t y0, y1;
      threefry2x32(p0, p1, 0u, (uint32_t)(i0 + w) * (uint32_t)BSZ + (uint32_t)j, y0, y1);
      const unsigned long long key =
          ((unsigned long long)((y0 ^ y1) >> 9) << 32) | (uint32_t)(~j);
      atomicMax(&swp[w], key);
    }
  }
  __syncthreads();
  if (t < SROWS) {
    pos_idx[i0 + t] = (int)(~(uint32_t)swp[t]);  // i itself always matches -> swp != 0
    const unsigned long long vn = swn[t];
    neg_idx[i0 + t] = (vn == 0ull) ? 0 : (int)(~(uint32_t)vn);
  }
}

// ---------------- Kernel 3: G = Fq * Fq^T, fp8 MX K=128, triangle, bf16 out ----------------
using int8v = __attribute__((ext_vector_type(8))) int;
using int4v = __attribute__((ext_vector_type(4))) int;
using f32x4 = __attribute__((ext_vector_type(4))) float;

__device__ __forceinline__ void async_load16(const void* g, void* l) {
  __builtin_amdgcn_global_load_lds((__attribute__((address_space(1))) void*)g,
                                   (__attribute__((address_space(3))) void*)l, 16, 0, 0);
}

// LDS layout: row r (128 B) holds 8 chunks of 16 B; chunk c stored at slot c ^ (r & 7).
// Staging realizes this by permuting the GLOBAL source chunk per lane.
__global__ __launch_bounds__(256) void gemm_kernel(const uint8_t* __restrict__ Fq,
                                                   uint16_t* __restrict__ Gb) {
  // Triangular block decode: p = by*(by+1)/2 + bx, bx <= by  (32x32 block grid)
  const int p = blockIdx.x;
  int by = (int)((sqrtf(8.0f * (float)p + 1.0f) - 1.0f) * 0.5f);
  if ((by + 1) * (by + 2) / 2 <= p) ++by;
  if (by * (by + 1) / 2 > p) --by;
  const int bx = p - by * (by + 1) / 2;

  __shared__ __align__(16) uint8_t lA[128 * 128];  // 16 KB
  __shared__ __align__(16) uint8_t lB[128 * 128];
  const int t = threadIdx.x;
  const int l = t & 63;
  const int w = t >> 6;
  const int wm = (w >> 1) * 64;
  const int wn = (w & 1) * 64;
  const int bm = bx * 128;
  const int bn = by * 128;

  f32x4 acc[4][4] = {};

  const int srow = t >> 3;  // 0..31
  const int scol = (((t & 7) ^ ((t >> 3) & 7)) << 4);  // XOR-swizzled source chunk
  const uint8_t* gA0 = Fq + (size_t)(bm + srow) * DIM + scol;
  const uint8_t* gB0 = Fq + (size_t)(bn + srow) * DIM + scol;

  // Fragment LDS byte offsets (iteration-invariant): row fra, chunks c0, c0+1
  const int fr = l & 15;
  const int c0 = (l >> 4) * 2;
  int offA[4][2], offB[4][2];
#pragma unroll
  for (int tm = 0; tm < 4; ++tm) {
    const int fra = wm + tm * 16 + fr, sw = fra & 7;
    offA[tm][0] = fra * 128 + ((c0 ^ sw) << 4);
    offA[tm][1] = fra * 128 + (((c0 + 1) ^ sw) << 4);
    const int frb = wn + tm * 16 + fr, sb = frb & 7;
    offB[tm][0] = frb * 128 + ((c0 ^ sb) << 4);
    offB[tm][1] = frb * 128 + (((c0 + 1) ^ sb) << 4);
  }

  for (int it = 0; it < 8; ++it) {  // K = 1024, BK = 128
    const int k0 = it * 128;
    __syncthreads();
#pragma unroll
    for (int ld = 0; ld < 4; ++ld) {
      async_load16(gA0 + (size_t)ld * 32 * DIM + k0, (char*)lA + (ld * 256 + t) * 16);
      async_load16(gB0 + (size_t)ld * 32 * DIM + k0, (char*)lB + (ld * 256 + t) * 16);
    }
    __syncthreads();
    int8v av[4], bv[4];
#pragma unroll
    for (int tm = 0; tm < 4; ++tm) {
      int4v alo = *(const int4v*)&lA[offA[tm][0]];
      int4v ahi = *(const int4v*)&lA[offA[tm][1]];
      av[tm] = __builtin_shufflevector(alo, ahi, 0, 1, 2, 3, 4, 5, 6, 7);
      int4v blo = *(const int4v*)&lB[offB[tm][0]];
      int4v bhi = *(const int4v*)&lB[offB[tm][1]];
      bv[tm] = __builtin_shufflevector(blo, bhi, 0, 1, 2, 3, 4, 5, 6, 7);
    }
#pragma unroll
    for (int tm = 0; tm < 4; ++tm)
#pragma unroll
      for (int tn = 0; tn < 4; ++tn)
        acc[tm][tn] = __builtin_amdgcn_mfma_scale_f32_16x16x128_f8f6f4(
            av[tm], bv[tn], acc[tm][tn],
            0, 0,                       // cbsz/blgp = fp8 e4m3
            0, 0x7F7F7F7F,              // scale A = 1.0 (E8M0 127)
            0, 0x7F7F7F7F);             // scale B = 1.0
  }
  // C/D layout: col = lane&15, row = (lane>>4)*4 + reg
  const int cr = (l >> 4) * 4;
  const int cc = l & 15;
#pragma unroll
  for (int tm = 0; tm < 4; ++tm)
#pragma unroll
    for (int tn = 0; tn < 4; ++tn) {
      const int row0 = bm + wm + tm * 16 + cr;
      const int col  = bn + wn + tn * 16 + cc;
      ushort h0 = f2bf(acc[tm][tn][0]), h1 = f2bf(acc[tm][tn][1]);
      ushort h2 = f2bf(acc[tm][tn][2]), h3 = f2bf(acc[tm][tn][3]);
      Gb[(size_t)(row0 + 0) * BSZ + col] = h0;
      Gb[(size_t)(row0 + 1) * BSZ + col] = h1;
      Gb[(size_t)(row0 + 2) * BSZ + col] = h2;
      Gb[(size_t)(row0 + 3) * BSZ + col] = h3;
      // Mirror tile (G symmetric): 4 consecutive rows -> contiguous ushort4 (8 B)
      ushort4 v = make_ushort4(h0, h1, h2, h3);
      *(ushort4*)&Gb[(size_t)col * BSZ + row0] = v;
    }
}

// ---------------- Kernel 4: loss, 1 row/block (4096 blocks), ticket finalize ----------------
__device__ __forceinline__ float bfl(uint32_t w) { return __uint_as_float(w << 16); }
__device__ __forceinline__ float bfh(uint32_t w) { return __uint_as_float(w & 0xFFFF0000u); }

__global__ __launch_bounds__(256) void loss_kernel(const uint16_t* __restrict__ Gb,
                                                   const float* __restrict__ norm2,
                                                   const float* __restrict__ sums,
                                                   const float* __restrict__ nv,
                                                   const int* __restrict__ pos_idx,
                                                   const int* __restrict__ neg_idx,
                                                   float* __restrict__ partial,
                                                   unsigned int* __restrict__ ticket,
                                                   float* __restrict__ out) {
  const int i = blockIdx.x, t = threadIdx.x;
  const int a = pos_idx[i], b = neg_idx[i];
  const float deps2 = (float)DIM * EPSV * EPSV;
  const float ca = norm2[a] - 2.0f * EPSV * sums[a] + deps2;
  const float cb = norm2[b] - 2.0f * EPSV * sums[b] + deps2;
  const uint4* Ga = (const uint4*)(Gb + (size_t)a * BSZ);
  const uint4* Gn = (const uint4*)(Gb + (size_t)b * BSZ);
  const float4* N4 = (const float4*)nv;
  // 16 entries per thread, all loads independent & coalesced (32 B/lane)
  uint4 ga[2], gn[2];
  float4 njv[4];
  ga[0] = Ga[t * 2]; ga[1] = Ga[t * 2 + 1];
  gn[0] = Gn[t * 2]; gn[1] = Gn[t * 2 + 1];
#pragma unroll
  for (int k = 0; k < 4; ++k) njv[k] = N4[t * 4 + k];
  float s = 0.f;
#pragma unroll
  for (int h = 0; h < 2; ++h) {
    const uint4 gau = ga[h], gnu = gn[h];
    float gav[8] = {bfl(gau.x), bfh(gau.x), bfl(gau.y), bfh(gau.y),
                    bfl(gau.z), bfh(gau.z), bfl(gau.w), bfh(gau.w)};
    float gnv[8] = {bfl(gnu.x), bfh(gnu.x), bfl(gnu.y), bfh(gnu.y),
                    bfl(gnu.z), bfh(gnu.z), bfl(gnu.w), bfh(gnu.w)};
    const float4 na = njv[h * 2], nb = njv[h * 2 + 1];
    float nj[8] = {na.x, na.y, na.z, na.w, nb.x, nb.y, nb.z, nb.w};
#pragma unroll
    for (int e = 0; e < 8; ++e) {
      const float dap = sqrtf(fmaxf(fmaf(-2.f, gav[e], nj[e] + ca), 1e-12f));
      const float dan = sqrtf(fmaxf(fmaf(-2.f, gnv[e], nj[e] + cb), 1e-12f));
      s += fmaxf(dap - dan + MARGINV, 0.f);
    }
  }
  for (int off = 32; off; off >>= 1) s += __shfl_xor(s, off);
  __shared__ float ps[4];
  __shared__ bool amLast;
  const int w = t >> 6, lane = t & 63;
  if (lane == 0) ps[w] = s;
  __syncthreads();
  if (t == 0) {
    partial[i] = (ps[0] + ps[1]) + (ps[2] + ps[3]);
    __threadfence();  // make partial visible at agent scope before ticket
    unsigned int old = __hip_atomic_fetch_add(ticket, 1u, __ATOMIC_ACQ_REL,
                                              __HIP_MEMORY_SCOPE_AGENT);
    amLast = (old == (unsigned int)(gridDim.x - 1));
  }
  __syncthreads();
  if (amLast) {
    float v = 0.f;
    for (int k = t; k < BSZ; k += 256)
      v += __hip_atomic_load(&partial[k], __ATOMIC_RELAXED, __HIP_MEMORY_SCOPE_AGENT);
    for (int off = 32; off; off >>= 1) v += __shfl_xor(v, off);
    if (lane == 0) ps[w] = v;
    __syncthreads();
    if (t == 0)
      out[0] = ((ps[0] + ps[1]) + (ps[2] + ps[3])) * (1.0f / ((float)BSZ * (float)BSZ));
  }
}

// ---------------- Launch ----------------
extern "C" void kernel_launch(void* const* d_in, const int* in_sizes, int n_in,
                              void* d_out, int out_size, void* d_ws, size_t ws_size,
                              hipStream_t stream) {
  const float* feat = (const float*)d_in[0];
  const int* labels = (const int*)d_in[1];
  float* out = (float*)d_out;

  char* ws = (char*)d_ws;
  uint16_t* Gb     = (uint16_t*)ws;                               // 32 MB (bf16 G)
  uint8_t* Fq      = (uint8_t*)(ws + (size_t)33554432);           // 4 MB
  float* norm2     = (float*)(ws + (size_t)37748736);             // 16 KB
  float* sums      = (float*)(ws + (size_t)37748736 + 16384);     // 16 KB
  float* nv        = (float*)(ws + (size_t)37748736 + 32768);     // 16 KB
  int* pos_idx     = (int*)  (ws + (size_t)37748736 + 49152);     // 16 KB
  int* neg_idx     = (int*)  (ws + (size_t)37748736 + 65536);     // 16 KB
  float* partial   = (float*)(ws + (size_t)37748736 + 81920);     // 16 KB
  unsigned int* tk = (unsigned int*)(ws + (size_t)37748736 + 98304);

  // JAX partitionable split: k_i = threefry(base_key=(0,42), (0, i))
  uint32_t k1a, k1b, k2a, k2b;
  threefry2x32(0u, 42u, 0u, 0u, k1a, k1b);  // k1 -> pos uniforms
  threefry2x32(0u, 42u, 0u, 1u, k2a, k2b);  // k2 -> neg uniforms

  prep_kernel<<<dim3(BSZ / 4), dim3(256), 0, stream>>>(feat, Fq, norm2, sums, nv, tk);
  sample_kernel<<<dim3(BSZ / SROWS), dim3(256), 0, stream>>>(labels, pos_idx, neg_idx,
                                                             k1a, k1b, k2a, k2b);
  gemm_kernel<<<dim3(528), dim3(256), 0, stream>>>(Fq, Gb);
  loss_kernel<<<dim3(BSZ), dim3(256), 0, stream>>>(Gb, norm2, sums, nv, pos_idx,
                                                   neg_idx, partial, tk, out);
}

// Round 7
// 145.919 us; speedup vs baseline: 2.2525x; 2.2525x over previous
//
#include <hip/hip_runtime.h>
#include <stdint.h>

// Problem constants (B=4096, D=1024 from setup_inputs)
#define BSZ 4096
#define DIM 1024
#define EPSV 1e-6f
#define MARGINV 0.3f
#define SROWS 4

// ---------------- Threefry-2x32 (bit-exact vs JAX lowering) ----------------
#define TF_ROT(x0, x1, r) { x0 += x1; x1 = ((x1 << r) | (x1 >> (32 - r))); x1 ^= x0; }

__host__ __device__ __forceinline__ void threefry2x32(uint32_t k0, uint32_t k1,
                                                      uint32_t c0, uint32_t c1,
                                                      uint32_t& o0, uint32_t& o1) {
  uint32_t ks2 = k0 ^ k1 ^ 0x1BD11BDAu;
  uint32_t x0 = c0 + k0;
  uint32_t x1 = c1 + k1;
  TF_ROT(x0, x1, 13) TF_ROT(x0, x1, 15) TF_ROT(x0, x1, 26) TF_ROT(x0, x1, 6)
  x0 += k1;  x1 += ks2 + 1u;
  TF_ROT(x0, x1, 17) TF_ROT(x0, x1, 29) TF_ROT(x0, x1, 16) TF_ROT(x0, x1, 24)
  x0 += ks2; x1 += k0 + 2u;
  TF_ROT(x0, x1, 13) TF_ROT(x0, x1, 15) TF_ROT(x0, x1, 26) TF_ROT(x0, x1, 6)
  x0 += k0;  x1 += k1 + 3u;
  TF_ROT(x0, x1, 17) TF_ROT(x0, x1, 29) TF_ROT(x0, x1, 16) TF_ROT(x0, x1, 24)
  x0 += k1;  x1 += ks2 + 4u;
  TF_ROT(x0, x1, 13) TF_ROT(x0, x1, 15) TF_ROT(x0, x1, 26) TF_ROT(x0, x1, 6)
  x0 += ks2; x1 += k0 + 5u;
  o0 = x0; o1 = x1;
}

__device__ __forceinline__ uint16_t f2bf(float f) {  // RNE float->bf16
  uint32_t u = __float_as_uint(f);
  u += 0x7FFFu + ((u >> 16) & 1u);
  return (uint16_t)(u >> 16);
}

// ---------------- Kernel 1: norms/sums/nv + fp8 convert ----------------
__global__ __launch_bounds__(256) void prep_kernel(const float* __restrict__ F,
                                                   uint8_t* __restrict__ Fq,
                                                   float* __restrict__ norm2,
                                                   float* __restrict__ sums,
                                                   float* __restrict__ nv) {
  const int w = threadIdx.x >> 6, l = threadIdx.x & 63;
  const int r = blockIdx.x * 4 + w;  // one wave per row
  const float4* src = (const float4*)(F + (size_t)r * DIM);
  uint32_t* dst = (uint32_t*)(Fq + (size_t)r * DIM);
  float s = 0.f, q = 0.f;
#pragma unroll
  for (int c = 0; c < 4; ++c) {
    float4 v = src[c * 64 + l];
    s += (v.x + v.y) + (v.z + v.w);
    q += v.x * v.x + v.y * v.y + v.z * v.z + v.w * v.w;
    int wd = 0;
    wd = __builtin_amdgcn_cvt_pk_fp8_f32(v.x, v.y, wd, false);  // bytes 0,1
    wd = __builtin_amdgcn_cvt_pk_fp8_f32(v.z, v.w, wd, true);   // bytes 2,3
    dst[c * 64 + l] = (uint32_t)wd;
  }
  for (int off = 32; off; off >>= 1) { s += __shfl_xor(s, off); q += __shfl_xor(q, off); }
  if (l == 0) {
    norm2[r] = q; sums[r] = s;
    nv[r] = q + 2.0f * EPSV * s;
  }
}

// ---------------- Kernel 2: triplet mining, 4 rows/block (labels amortized) ----------------
__global__ __launch_bounds__(256) void sample_kernel(const int* __restrict__ labels,
                                                     int* __restrict__ pos_idx,
                                                     int* __restrict__ neg_idx,
                                                     uint32_t p0, uint32_t p1,
                                                     uint32_t n0, uint32_t n1) {
  __shared__ int plist[SROWS][64];
  __shared__ int pcnt[SROWS];
  __shared__ unsigned long long swp[SROWS];
  __shared__ unsigned long long swn[SROWS];
  const int t = threadIdx.x;
  const int i0 = blockIdx.x * SROWS;
  if (t < SROWS) { pcnt[t] = 0; swp[t] = 0ull; swn[t] = 0ull; }
  int lj[16];
#pragma unroll
  for (int c = 0; c < 16; ++c) lj[c] = labels[c * 256 + t];
  __syncthreads();
  const int lane = t & 63;
  for (int r = 0; r < SROWS; ++r) {
    const int li = labels[i0 + r];  // block-uniform -> scalar load
    const uint32_t base = (uint32_t)(i0 + r) * (uint32_t)BSZ + (uint32_t)t;
    uint32_t bestn = 0u;
#pragma unroll
    for (int c = 0; c < 16; ++c) {
      uint32_t y0, y1;
      threefry2x32(n0, n1, 0u, base + (uint32_t)(c * 256), y0, y1);
      const uint32_t pack = (((y0 ^ y1) >> 9) << 4) | (uint32_t)(15 - c);
      const bool eq = (lj[c] == li);
      if (eq) {  // rare: ~8 lanes per row
        int sl = atomicAdd(&pcnt[r], 1);
        if (sl < 64) plist[r][sl] = c * 256 + t;
      }
      const uint32_t v = eq ? 0u : pack;
      if (v > bestn) bestn = v;
    }
    // lane-local 32-bit -> global 64-bit key
    unsigned long long keyn = 0ull;
    if (bestn) {
      const int c = 15 - (int)(bestn & 15u);
      const int j = c * 256 + t;
      keyn = ((unsigned long long)(bestn >> 4) << 32) | (uint32_t)(~j);
    }
    for (int off = 32; off; off >>= 1) {
      unsigned long long o = __shfl_xor(keyn, off);
      if (o > keyn) keyn = o;
    }
    if (lane == 0) atomicMax(&swn[r], keyn);
  }
  __syncthreads();  // fences plist/pcnt/swn
  // POS phase: wave w handles row w's candidate list
  const int w = t >> 6;
  {
    const int cnt = pcnt[w] < 64 ? pcnt[w] : 64;
    if (lane < cnt) {
      const int j = plist[w][lane];
      uint32_t y0, y1;
      threefry2x32(p0, p1, 0u, (uint32_t)(i0 + w) * (uint32_t)BSZ + (uint32_t)j, y0, y1);
      const unsigned long long key =
          ((unsigned long long)((y0 ^ y1) >> 9) << 32) | (uint32_t)(~j);
      atomicMax(&swp[w], key);
    }
  }
  __syncthreads();
  if (t < SROWS) {
    pos_idx[i0 + t] = (int)(~(uint32_t)swp[t]);  // i itself always matches -> swp != 0
    const unsigned long long vn = swn[t];
    neg_idx[i0 + t] = (vn == 0ull) ? 0 : (int)(~(uint32_t)vn);
  }
}

// ---------------- Kernel 3: G = Fq * Fq^T, fp8 MX K=128, triangle, bf16 out ----------------
using int8v = __attribute__((ext_vector_type(8))) int;
using int4v = __attribute__((ext_vector_type(4))) int;
using f32x4 = __attribute__((ext_vector_type(4))) float;

__device__ __forceinline__ void async_load16(const void* g, void* l) {
  __builtin_amdgcn_global_load_lds((__attribute__((address_space(1))) void*)g,
                                   (__attribute__((address_space(3))) void*)l, 16, 0, 0);
}

// LDS layout: row r (128 B) holds 8 chunks of 16 B; chunk c stored at slot c ^ (r & 7).
__global__ __launch_bounds__(256) void gemm_kernel(const uint8_t* __restrict__ Fq,
                                                   uint16_t* __restrict__ Gb) {
  // Triangular block decode: p = by*(by+1)/2 + bx, bx <= by  (32x32 block grid)
  const int p = blockIdx.x;
  int by = (int)((sqrtf(8.0f * (float)p + 1.0f) - 1.0f) * 0.5f);
  if ((by + 1) * (by + 2) / 2 <= p) ++by;
  if (by * (by + 1) / 2 > p) --by;
  const int bx = p - by * (by + 1) / 2;

  __shared__ __align__(16) uint8_t lA[128 * 128];  // 16 KB
  __shared__ __align__(16) uint8_t lB[128 * 128];
  const int t = threadIdx.x;
  const int l = t & 63;
  const int w = t >> 6;
  const int wm = (w >> 1) * 64;
  const int wn = (w & 1) * 64;
  const int bm = bx * 128;
  const int bn = by * 128;

  f32x4 acc[4][4] = {};

  const int srow = t >> 3;  // 0..31
  const int scol = (((t & 7) ^ ((t >> 3) & 7)) << 4);  // XOR-swizzled source chunk
  const uint8_t* gA0 = Fq + (size_t)(bm + srow) * DIM + scol;
  const uint8_t* gB0 = Fq + (size_t)(bn + srow) * DIM + scol;

  // Fragment LDS byte offsets (iteration-invariant): row fra, chunks c0, c0+1
  const int fr = l & 15;
  const int c0 = (l >> 4) * 2;
  int offA[4][2], offB[4][2];
#pragma unroll
  for (int tm = 0; tm < 4; ++tm) {
    const int fra = wm + tm * 16 + fr, sw = fra & 7;
    offA[tm][0] = fra * 128 + ((c0 ^ sw) << 4);
    offA[tm][1] = fra * 128 + (((c0 + 1) ^ sw) << 4);
    const int frb = wn + tm * 16 + fr, sb = frb & 7;
    offB[tm][0] = frb * 128 + ((c0 ^ sb) << 4);
    offB[tm][1] = frb * 128 + (((c0 + 1) ^ sb) << 4);
  }

  for (int it = 0; it < 8; ++it) {  // K = 1024, BK = 128
    const int k0 = it * 128;
    __syncthreads();
#pragma unroll
    for (int ld = 0; ld < 4; ++ld) {
      async_load16(gA0 + (size_t)ld * 32 * DIM + k0, (char*)lA + (ld * 256 + t) * 16);
      async_load16(gB0 + (size_t)ld * 32 * DIM + k0, (char*)lB + (ld * 256 + t) * 16);
    }
    __syncthreads();
    int8v av[4], bv[4];
#pragma unroll
    for (int tm = 0; tm < 4; ++tm) {
      int4v alo = *(const int4v*)&lA[offA[tm][0]];
      int4v ahi = *(const int4v*)&lA[offA[tm][1]];
      av[tm] = __builtin_shufflevector(alo, ahi, 0, 1, 2, 3, 4, 5, 6, 7);
      int4v blo = *(const int4v*)&lB[offB[tm][0]];
      int4v bhi = *(const int4v*)&lB[offB[tm][1]];
      bv[tm] = __builtin_shufflevector(blo, bhi, 0, 1, 2, 3, 4, 5, 6, 7);
    }
#pragma unroll
    for (int tm = 0; tm < 4; ++tm)
#pragma unroll
      for (int tn = 0; tn < 4; ++tn)
        acc[tm][tn] = __builtin_amdgcn_mfma_scale_f32_16x16x128_f8f6f4(
            av[tm], bv[tn], acc[tm][tn],
            0, 0,                       // cbsz/blgp = fp8 e4m3
            0, 0x7F7F7F7F,              // scale A = 1.0 (E8M0 127)
            0, 0x7F7F7F7F);             // scale B = 1.0
  }
  // C/D layout: col = lane&15, row = (lane>>4)*4 + reg
  const int cr = (l >> 4) * 4;
  const int cc = l & 15;
#pragma unroll
  for (int tm = 0; tm < 4; ++tm)
#pragma unroll
    for (int tn = 0; tn < 4; ++tn) {
      const int row0 = bm + wm + tm * 16 + cr;
      const int col  = bn + wn + tn * 16 + cc;
      ushort h0 = f2bf(acc[tm][tn][0]), h1 = f2bf(acc[tm][tn][1]);
      ushort h2 = f2bf(acc[tm][tn][2]), h3 = f2bf(acc[tm][tn][3]);
      Gb[(size_t)(row0 + 0) * BSZ + col] = h0;
      Gb[(size_t)(row0 + 1) * BSZ + col] = h1;
      Gb[(size_t)(row0 + 2) * BSZ + col] = h2;
      Gb[(size_t)(row0 + 3) * BSZ + col] = h3;
      // Mirror tile (G symmetric): 4 consecutive rows -> contiguous ushort4 (8 B)
      ushort4 v = make_ushort4(h0, h1, h2, h3);
      *(ushort4*)&Gb[(size_t)col * BSZ + row0] = v;
    }
}

// ---------------- Kernel 4: loss, 1 row/block, plain partial store ----------------
__device__ __forceinline__ float bfl(uint32_t w) { return __uint_as_float(w << 16); }
__device__ __forceinline__ float bfh(uint32_t w) { return __uint_as_float(w & 0xFFFF0000u); }

__global__ __launch_bounds__(256) void loss_kernel(const uint16_t* __restrict__ Gb,
                                                   const float* __restrict__ norm2,
                                                   const float* __restrict__ sums,
                                                   const float* __restrict__ nv,
                                                   const int* __restrict__ pos_idx,
                                                   const int* __restrict__ neg_idx,
                                                   float* __restrict__ partial) {
  const int i = blockIdx.x, t = threadIdx.x;
  const int a = pos_idx[i], b = neg_idx[i];
  const float deps2 = (float)DIM * EPSV * EPSV;
  const float ca = norm2[a] - 2.0f * EPSV * sums[a] + deps2;
  const float cb = norm2[b] - 2.0f * EPSV * sums[b] + deps2;
  const uint4* Ga = (const uint4*)(Gb + (size_t)a * BSZ);
  const uint4* Gn = (const uint4*)(Gb + (size_t)b * BSZ);
  const float4* N4 = (const float4*)nv;
  // 16 entries per thread, all loads independent & coalesced (32 B/lane)
  uint4 ga[2], gn[2];
  float4 njv[4];
  ga[0] = Ga[t * 2]; ga[1] = Ga[t * 2 + 1];
  gn[0] = Gn[t * 2]; gn[1] = Gn[t * 2 + 1];
#pragma unroll
  for (int k = 0; k < 4; ++k) njv[k] = N4[t * 4 + k];
  float s = 0.f;
#pragma unroll
  for (int h = 0; h < 2; ++h) {
    const uint4 gau = ga[h], gnu = gn[h];
    float gav[8] = {bfl(gau.x), bfh(gau.x), bfl(gau.y), bfh(gau.y),
                    bfl(gau.z), bfh(gau.z), bfl(gau.w), bfh(gau.w)};
    float gnv[8] = {bfl(gnu.x), bfh(gnu.x), bfl(gnu.y), bfh(gnu.y),
                    bfl(gnu.z), bfh(gnu.z), bfl(gnu.w), bfh(gnu.w)};
    const float4 na = njv[h * 2], nb = njv[h * 2 + 1];
    float nj[8] = {na.x, na.y, na.z, na.w, nb.x, nb.y, nb.z, nb.w};
#pragma unroll
    for (int e = 0; e < 8; ++e) {
      const float dap = sqrtf(fmaxf(fmaf(-2.f, gav[e], nj[e] + ca), 1e-12f));
      const float dan = sqrtf(fmaxf(fmaf(-2.f, gnv[e], nj[e] + cb), 1e-12f));
      s += fmaxf(dap - dan + MARGINV, 0.f);
    }
  }
  for (int off = 32; off; off >>= 1) s += __shfl_xor(s, off);
  __shared__ float ps[4];
  const int w = t >> 6, lane = t & 63;
  if (lane == 0) ps[w] = s;
  __syncthreads();
  if (t == 0) partial[i] = (ps[0] + ps[1]) + (ps[2] + ps[3]);  // plain store; kernel
  // boundary (stream order) publishes it to the finalize launch — no fence/ticket.
}

// ---------------- Kernel 5: finalize (1 block) ----------------
__global__ __launch_bounds__(256) void finalize_kernel(const float* __restrict__ partial,
                                                       float* __restrict__ out) {
  const int t = threadIdx.x;
  const float4* P4 = (const float4*)partial;
  float s = 0.f;
#pragma unroll
  for (int k = 0; k < 4; ++k) {  // 4096 partials = 1024 float4
    float4 v = P4[k * 256 + t];
    s += (v.x + v.y) + (v.z + v.w);
  }
  for (int off = 32; off; off >>= 1) s += __shfl_xor(s, off);
  __shared__ float ps[4];
  const int w = t >> 6, lane = t & 63;
  if (lane == 0) ps[w] = s;
  __syncthreads();
  if (t == 0)
    out[0] = ((ps[0] + ps[1]) + (ps[2] + ps[3])) * (1.0f / ((float)BSZ * (float)BSZ));
}

// ---------------- Launch ----------------
extern "C" void kernel_launch(void* const* d_in, const int* in_sizes, int n_in,
                              void* d_out, int out_size, void* d_ws, size_t ws_size,
                              hipStream_t stream) {
  const float* feat = (const float*)d_in[0];
  const int* labels = (const int*)d_in[1];
  float* out = (float*)d_out;

  char* ws = (char*)d_ws;
  uint16_t* Gb     = (uint16_t*)ws;                               // 32 MB (bf16 G)
  uint8_t* Fq      = (uint8_t*)(ws + (size_t)33554432);           // 4 MB
  float* norm2     = (float*)(ws + (size_t)37748736);             // 16 KB
  float* sums      = (float*)(ws + (size_t)37748736 + 16384);     // 16 KB
  float* nv        = (float*)(ws + (size_t)37748736 + 32768);     // 16 KB
  int* pos_idx     = (int*)  (ws + (size_t)37748736 + 49152);     // 16 KB
  int* neg_idx     = (int*)  (ws + (size_t)37748736 + 65536);     // 16 KB
  float* partial   = (float*)(ws + (size_t)37748736 + 81920);     // 16 KB

  // JAX partitionable split: k_i = threefry(base_key=(0,42), (0, i))
  uint32_t k1a, k1b, k2a, k2b;
  threefry2x32(0u, 42u, 0u, 0u, k1a, k1b);  // k1 -> pos uniforms
  threefry2x32(0u, 42u, 0u, 1u, k2a, k2b);  // k2 -> neg uniforms

  prep_kernel<<<dim3(BSZ / 4), dim3(256), 0, stream>>>(feat, Fq, norm2, sums, nv);
  sample_kernel<<<dim3(BSZ / SROWS), dim3(256), 0, stream>>>(labels, pos_idx, neg_idx,
                                                             k1a, k1b, k2a, k2b);
  gemm_kernel<<<dim3(528), dim3(256), 0, stream>>>(Fq, Gb);
  loss_kernel<<<dim3(BSZ), dim3(256), 0, stream>>>(Gb, norm2, sums, nv, pos_idx,
                                                   neg_idx, partial);
  finalize_kernel<<<dim3(1), dim3(256), 0, stream>>>(partial, out);
}

// Round 8
// 143.191 us; speedup vs baseline: 2.2955x; 1.0191x over previous
//
#include <hip/hip_runtime.h>
#include <stdint.h>

// Problem constants (B=4096, D=1024 from setup_inputs)
#define BSZ 4096
#define DIM 1024
#define EPSV 1e-6f
#define MARGINV 0.3f
#define SROWS 4
#define SAMPLE_BLOCKS (BSZ / SROWS)   // 1024, blocks [0, 1024)
#define PREP_BLOCKS (BSZ / 4)         // 1024, blocks [1024, 2048)

// ---------------- Threefry-2x32 (bit-exact vs JAX lowering) ----------------
#define TF_ROT(x0, x1, r) { x0 += x1; x1 = ((x1 << r) | (x1 >> (32 - r))); x1 ^= x0; }

__host__ __device__ __forceinline__ void threefry2x32(uint32_t k0, uint32_t k1,
                                                      uint32_t c0, uint32_t c1,
                                                      uint32_t& o0, uint32_t& o1) {
  uint32_t ks2 = k0 ^ k1 ^ 0x1BD11BDAu;
  uint32_t x0 = c0 + k0;
  uint32_t x1 = c1 + k1;
  TF_ROT(x0, x1, 13) TF_ROT(x0, x1, 15) TF_ROT(x0, x1, 26) TF_ROT(x0, x1, 6)
  x0 += k1;  x1 += ks2 + 1u;
  TF_ROT(x0, x1, 17) TF_ROT(x0, x1, 29) TF_ROT(x0, x1, 16) TF_ROT(x0, x1, 24)
  x0 += ks2; x1 += k0 + 2u;
  TF_ROT(x0, x1, 13) TF_ROT(x0, x1, 15) TF_ROT(x0, x1, 26) TF_ROT(x0, x1, 6)
  x0 += k0;  x1 += k1 + 3u;
  TF_ROT(x0, x1, 17) TF_ROT(x0, x1, 29) TF_ROT(x0, x1, 16) TF_ROT(x0, x1, 24)
  x0 += k1;  x1 += ks2 + 4u;
  TF_ROT(x0, x1, 13) TF_ROT(x0, x1, 15) TF_ROT(x0, x1, 26) TF_ROT(x0, x1, 6)
  x0 += ks2; x1 += k0 + 5u;
  o0 = x0; o1 = x1;
}

__device__ __forceinline__ uint16_t f2bf(float f) {  // RNE float->bf16
  uint32_t u = __float_as_uint(f);
  u += 0x7FFFu + ((u >> 16) & 1u);
  return (uint16_t)(u >> 16);
}

// ---------------- Kernel 1: FUSED prep + triplet mining ----------------
// Blocks [0,1024): sampling (VALU-bound long pole, dispatched first).
// Blocks [1024,2048): prep (HBM-bound, overlaps with sampling).
__global__ __launch_bounds__(256) void prep_sample_kernel(
    const float* __restrict__ F, uint8_t* __restrict__ Fq,
    float* __restrict__ norm2, float* __restrict__ sums, float* __restrict__ nv,
    const int* __restrict__ labels, int* __restrict__ pos_idx, int* __restrict__ neg_idx,
    uint32_t p0, uint32_t p1, uint32_t n0, uint32_t n1) {
  const int t = threadIdx.x;
  if (blockIdx.x >= SAMPLE_BLOCKS) {
    // ================= PREP branch: 4 rows/block, one wave per row =================
    const int w = t >> 6, l = t & 63;
    const int r = (blockIdx.x - SAMPLE_BLOCKS) * 4 + w;
    const float4* src = (const float4*)(F + (size_t)r * DIM);
    uint32_t* dst = (uint32_t*)(Fq + (size_t)r * DIM);
    float s = 0.f, q = 0.f;
#pragma unroll
    for (int c = 0; c < 4; ++c) {
      float4 v = src[c * 64 + l];
      s += (v.x + v.y) + (v.z + v.w);
      q += v.x * v.x + v.y * v.y + v.z * v.z + v.w * v.w;
      int wd = 0;
      wd = __builtin_amdgcn_cvt_pk_fp8_f32(v.x, v.y, wd, false);  // bytes 0,1
      wd = __builtin_amdgcn_cvt_pk_fp8_f32(v.z, v.w, wd, true);   // bytes 2,3
      dst[c * 64 + l] = (uint32_t)wd;
    }
    for (int off = 32; off; off >>= 1) { s += __shfl_xor(s, off); q += __shfl_xor(q, off); }
    if (l == 0) {
      norm2[r] = q; sums[r] = s;
      nv[r] = q + 2.0f * EPSV * s;
    }
    return;
  }
  // ================= SAMPLE branch: 4 rows/block =================
  __shared__ int plist[SROWS][64];
  __shared__ int pcnt[SROWS];
  __shared__ unsigned long long swp[SROWS];
  __shared__ unsigned long long swn[SROWS];
  const int i0 = blockIdx.x * SROWS;
  if (t < SROWS) { pcnt[t] = 0; swp[t] = 0ull; swn[t] = 0ull; }
  int lj[16];
#pragma unroll
  for (int c = 0; c < 16; ++c) lj[c] = labels[c * 256 + t];
  __syncthreads();
  const int lane = t & 63;
  for (int r = 0; r < SROWS; ++r) {
    const int li = labels[i0 + r];  // block-uniform -> scalar load
    const uint32_t base = (uint32_t)(i0 + r) * (uint32_t)BSZ + (uint32_t)t;
    uint32_t bestn = 0u;
#pragma unroll
    for (int c = 0; c < 16; ++c) {
      uint32_t y0, y1;
      threefry2x32(n0, n1, 0u, base + (uint32_t)(c * 256), y0, y1);
      // ((y>>9)<<4)|(15-c) == ((y>>5)&~15)|(15-c) -> v_and_or_b32
      const uint32_t pack = (((y0 ^ y1) >> 5) & 0xFFFFFFF0u) | (uint32_t)(15 - c);
      const bool eq = (lj[c] == li);
      if (eq) {  // rare (~8 lanes/row); exec-mask branch machinery is SALU (co-issued)
        int sl = atomicAdd(&pcnt[r], 1);
        if (sl < 64) plist[r][sl] = c * 256 + t;
      }
      const uint32_t v = eq ? 0u : pack;
      if (v > bestn) bestn = v;
    }
    // lane-local 32-bit -> global 64-bit key (tie -> lower j, matching JAX argmax)
    unsigned long long keyn = 0ull;
    if (bestn) {
      const int c = 15 - (int)(bestn & 15u);
      const int j = c * 256 + t;
      keyn = ((unsigned long long)(bestn >> 4) << 32) | (uint32_t)(~j);
    }
    for (int off = 32; off; off >>= 1) {
      unsigned long long o = __shfl_xor(keyn, off);
      if (o > keyn) keyn = o;
    }
    if (lane == 0) atomicMax(&swn[r], keyn);
  }
  __syncthreads();  // fences plist/pcnt/swn
  // POS phase: wave w handles row w's candidate list (~8 entries)
  const int w = t >> 6;
  {
    const int cnt = pcnt[w] < 64 ? pcnt[w] : 64;
    if (lane < cnt) {
      const int j = plist[w][lane];
      uint32_t y0, y1;
      threefry2x32(p0, p1, 0u, (uint32_t)(i0 + w) * (uint32_t)BSZ + (uint32_t)j, y0, y1);
      const unsigned long long key =
          ((unsigned long long)((y0 ^ y1) >> 9) << 32) | (uint32_t)(~j);
      atomicMax(&swp[w], key);
    }
  }
  __syncthreads();
  if (t < SROWS) {
    pos_idx[i0 + t] = (int)(~(uint32_t)swp[t]);  // i itself always matches -> swp != 0
    const unsigned long long vn = swn[t];
    neg_idx[i0 + t] = (vn == 0ull) ? 0 : (int)(~(uint32_t)vn);
  }
}

// ---------------- Kernel 2: G = Fq * Fq^T, fp8 MX K=128, triangle, bf16 out ----------------
using int8v = __attribute__((ext_vector_type(8))) int;
using int4v = __attribute__((ext_vector_type(4))) int;
using f32x4 = __attribute__((ext_vector_type(4))) float;

__device__ __forceinline__ void async_load16(const void* g, void* l) {
  __builtin_amdgcn_global_load_lds((__attribute__((address_space(1))) void*)g,
                                   (__attribute__((address_space(3))) void*)l, 16, 0, 0);
}

// LDS layout: row r (128 B) holds 8 chunks of 16 B; chunk c stored at slot c ^ (r & 7).
__global__ __launch_bounds__(256) void gemm_kernel(const uint8_t* __restrict__ Fq,
                                                   uint16_t* __restrict__ Gb) {
  // Triangular block decode: p = by*(by+1)/2 + bx, bx <= by  (32x32 block grid)
  const int p = blockIdx.x;
  int by = (int)((sqrtf(8.0f * (float)p + 1.0f) - 1.0f) * 0.5f);
  if ((by + 1) * (by + 2) / 2 <= p) ++by;
  if (by * (by + 1) / 2 > p) --by;
  const int bx = p - by * (by + 1) / 2;

  __shared__ __align__(16) uint8_t lA[128 * 128];  // 16 KB
  __shared__ __align__(16) uint8_t lB[128 * 128];
  const int t = threadIdx.x;
  const int l = t & 63;
  const int w = t >> 6;
  const int wm = (w >> 1) * 64;
  const int wn = (w & 1) * 64;
  const int bm = bx * 128;
  const int bn = by * 128;

  f32x4 acc[4][4] = {};

  const int srow = t >> 3;  // 0..31
  const int scol = (((t & 7) ^ ((t >> 3) & 7)) << 4);  // XOR-swizzled source chunk
  const uint8_t* gA0 = Fq + (size_t)(bm + srow) * DIM + scol;
  const uint8_t* gB0 = Fq + (size_t)(bn + srow) * DIM + scol;

  // Fragment LDS byte offsets (iteration-invariant): row fra, chunks c0, c0+1
  const int fr = l & 15;
  const int c0 = (l >> 4) * 2;
  int offA[4][2], offB[4][2];
#pragma unroll
  for (int tm = 0; tm < 4; ++tm) {
    const int fra = wm + tm * 16 + fr, sw = fra & 7;
    offA[tm][0] = fra * 128 + ((c0 ^ sw) << 4);
    offA[tm][1] = fra * 128 + (((c0 + 1) ^ sw) << 4);
    const int frb = wn + tm * 16 + fr, sb = frb & 7;
    offB[tm][0] = frb * 128 + ((c0 ^ sb) << 4);
    offB[tm][1] = frb * 128 + (((c0 + 1) ^ sb) << 4);
  }

  for (int it = 0; it < 8; ++it) {  // K = 1024, BK = 128
    const int k0 = it * 128;
    __syncthreads();
#pragma unroll
    for (int ld = 0; ld < 4; ++ld) {
      async_load16(gA0 + (size_t)ld * 32 * DIM + k0, (char*)lA + (ld * 256 + t) * 16);
      async_load16(gB0 + (size_t)ld * 32 * DIM + k0, (char*)lB + (ld * 256 + t) * 16);
    }
    __syncthreads();
    int8v av[4], bv[4];
#pragma unroll
    for (int tm = 0; tm < 4; ++tm) {
      int4v alo = *(const int4v*)&lA[offA[tm][0]];
      int4v ahi = *(const int4v*)&lA[offA[tm][1]];
      av[tm] = __builtin_shufflevector(alo, ahi, 0, 1, 2, 3, 4, 5, 6, 7);
      int4v blo = *(const int4v*)&lB[offB[tm][0]];
      int4v bhi = *(const int4v*)&lB[offB[tm][1]];
      bv[tm] = __builtin_shufflevector(blo, bhi, 0, 1, 2, 3, 4, 5, 6, 7);
    }
#pragma unroll
    for (int tm = 0; tm < 4; ++tm)
#pragma unroll
      for (int tn = 0; tn < 4; ++tn)
        acc[tm][tn] = __builtin_amdgcn_mfma_scale_f32_16x16x128_f8f6f4(
            av[tm], bv[tn], acc[tm][tn],
            0, 0,                       // cbsz/blgp = fp8 e4m3
            0, 0x7F7F7F7F,              // scale A = 1.0 (E8M0 127)
            0, 0x7F7F7F7F);             // scale B = 1.0
  }
  // C/D layout: col = lane&15, row = (lane>>4)*4 + reg
  const int cr = (l >> 4) * 4;
  const int cc = l & 15;
#pragma unroll
  for (int tm = 0; tm < 4; ++tm)
#pragma unroll
    for (int tn = 0; tn < 4; ++tn) {
      const int row0 = bm + wm + tm * 16 + cr;
      const int col  = bn + wn + tn * 16 + cc;
      ushort h0 = f2bf(acc[tm][tn][0]), h1 = f2bf(acc[tm][tn][1]);
      ushort h2 = f2bf(acc[tm][tn][2]), h3 = f2bf(acc[tm][tn][3]);
      Gb[(size_t)(row0 + 0) * BSZ + col] = h0;
      Gb[(size_t)(row0 + 1) * BSZ + col] = h1;
      Gb[(size_t)(row0 + 2) * BSZ + col] = h2;
      Gb[(size_t)(row0 + 3) * BSZ + col] = h3;
      // Mirror tile (G symmetric): 4 consecutive rows -> contiguous ushort4 (8 B)
      ushort4 v = make_ushort4(h0, h1, h2, h3);
      *(ushort4*)&Gb[(size_t)col * BSZ + row0] = v;
    }
}

// ---------------- Kernel 3: loss, 1 row/block, plain partial store ----------------
__device__ __forceinline__ float bfl(uint32_t w) { return __uint_as_float(w << 16); }
__device__ __forceinline__ float bfh(uint32_t w) { return __uint_as_float(w & 0xFFFF0000u); }

__global__ __launch_bounds__(256) void loss_kernel(const uint16_t* __restrict__ Gb,
                                                   const float* __restrict__ norm2,
                                                   const float* __restrict__ sums,
                                                   const float* __restrict__ nv,
                                                   const int* __restrict__ pos_idx,
                                                   const int* __restrict__ neg_idx,
                                                   float* __restrict__ partial) {
  const int i = blockIdx.x, t = threadIdx.x;
  const int a = pos_idx[i], b = neg_idx[i];
  const float deps2 = (float)DIM * EPSV * EPSV;
  const float ca = norm2[a] - 2.0f * EPSV * sums[a] + deps2;
  const float cb = norm2[b] - 2.0f * EPSV * sums[b] + deps2;
  const uint4* Ga = (const uint4*)(Gb + (size_t)a * BSZ);
  const uint4* Gn = (const uint4*)(Gb + (size_t)b * BSZ);
  const float4* N4 = (const float4*)nv;
  // 16 entries per thread, all loads independent & coalesced (32 B/lane)
  uint4 ga[2], gn[2];
  float4 njv[4];
  ga[0] = Ga[t * 2]; ga[1] = Ga[t * 2 + 1];
  gn[0] = Gn[t * 2]; gn[1] = Gn[t * 2 + 1];
#pragma unroll
  for (int k = 0; k < 4; ++k) njv[k] = N4[t * 4 + k];
  float s = 0.f;
#pragma unroll
  for (int h = 0; h < 2; ++h) {
    const uint4 gau = ga[h], gnu = gn[h];
    float gav[8] = {bfl(gau.x), bfh(gau.x), bfl(gau.y), bfh(gau.y),
                    bfl(gau.z), bfh(gau.z), bfl(gau.w), bfh(gau.w)};
    float gnv[8] = {bfl(gnu.x), bfh(gnu.x), bfl(gnu.y), bfh(gnu.y),
                    bfl(gnu.z), bfh(gnu.z), bfl(gnu.w), bfh(gnu.w)};
    const float4 na = njv[h * 2], nb = njv[h * 2 + 1];
    float nj[8] = {na.x, na.y, na.z, na.w, nb.x, nb.y, nb.z, nb.w};
#pragma unroll
    for (int e = 0; e < 8; ++e) {
      const float dap = sqrtf(fmaxf(fmaf(-2.f, gav[e], nj[e] + ca), 1e-12f));
      const float dan = sqrtf(fmaxf(fmaf(-2.f, gnv[e], nj[e] + cb), 1e-12f));
      s += fmaxf(dap - dan + MARGINV, 0.f);
    }
  }
  for (int off = 32; off; off >>= 1) s += __shfl_xor(s, off);
  __shared__ float ps[4];
  const int w = t >> 6, lane = t & 63;
  if (lane == 0) ps[w] = s;
  __syncthreads();
  if (t == 0) partial[i] = (ps[0] + ps[1]) + (ps[2] + ps[3]);  // plain store; the
  // kernel boundary (stream order) publishes it to finalize — no fence/ticket
  // (R6 lesson: per-block agent-scope tickets serialize at ~50 ns each).
}

// ---------------- Kernel 4: finalize (1 block) ----------------
__global__ __launch_bounds__(256) void finalize_kernel(const float* __restrict__ partial,
                                                       float* __restrict__ out) {
  const int t = threadIdx.x;
  const float4* P4 = (const float4*)partial;
  float s = 0.f;
#pragma unroll
  for (int k = 0; k < 4; ++k) {  // 4096 partials = 1024 float4
    float4 v = P4[k * 256 + t];
    s += (v.x + v.y) + (v.z + v.w);
  }
  for (int off = 32; off; off >>= 1) s += __shfl_xor(s, off);
  __shared__ float ps[4];
  const int w = t >> 6, lane = t & 63;
  if (lane == 0) ps[w] = s;
  __syncthreads();
  if (t == 0)
    out[0] = ((ps[0] + ps[1]) + (ps[2] + ps[3])) * (1.0f / ((float)BSZ * (float)BSZ));
}

// ---------------- Launch ----------------
extern "C" void kernel_launch(void* const* d_in, const int* in_sizes, int n_in,
                              void* d_out, int out_size, void* d_ws, size_t ws_size,
                              hipStream_t stream) {
  const float* feat = (const float*)d_in[0];
  const int* labels = (const int*)d_in[1];
  float* out = (float*)d_out;

  char* ws = (char*)d_ws;
  uint16_t* Gb     = (uint16_t*)ws;                               // 32 MB (bf16 G)
  uint8_t* Fq      = (uint8_t*)(ws + (size_t)33554432);           // 4 MB
  float* norm2     = (float*)(ws + (size_t)37748736);             // 16 KB
  float* sums      = (float*)(ws + (size_t)37748736 + 16384);     // 16 KB
  float* nv        = (float*)(ws + (size_t)37748736 + 32768);     // 16 KB
  int* pos_idx     = (int*)  (ws + (size_t)37748736 + 49152);     // 16 KB
  int* neg_idx     = (int*)  (ws + (size_t)37748736 + 65536);     // 16 KB
  float* partial   = (float*)(ws + (size_t)37748736 + 81920);     // 16 KB

  // JAX partitionable split: k_i = threefry(base_key=(0,42), (0, i))
  uint32_t k1a, k1b, k2a, k2b;
  threefry2x32(0u, 42u, 0u, 0u, k1a, k1b);  // k1 -> pos uniforms
  threefry2x32(0u, 42u, 0u, 1u, k2a, k2b);  // k2 -> neg uniforms

  prep_sample_kernel<<<dim3(SAMPLE_BLOCKS + PREP_BLOCKS), dim3(256), 0, stream>>>(
      feat, Fq, norm2, sums, nv, labels, pos_idx, neg_idx, k1a, k1b, k2a, k2b);
  gemm_kernel<<<dim3(528), dim3(256), 0, stream>>>(Fq, Gb);
  loss_kernel<<<dim3(BSZ), dim3(256), 0, stream>>>(Gb, norm2, sums, nv, pos_idx,
                                                   neg_idx, partial);
  finalize_kernel<<<dim3(1), dim3(256), 0, stream>>>(partial, out);
}

// Round 9
// 143.052 us; speedup vs baseline: 2.2977x; 1.0010x over previous
//
#include <hip/hip_runtime.h>
#include <stdint.h>

// Problem constants (B=4096, D=1024 from setup_inputs)
#define BSZ 4096
#define DIM 1024
#define EPSV 1e-6f
#define MARGINV 0.3f
#define SROWS 4
#define SAMPLE_BLOCKS (BSZ / SROWS)   // 1024, blocks [0, 1024)
#define PREP_BLOCKS (BSZ / 4)         // 1024, blocks [1024, 2048)

// ---------------- Threefry-2x32 (bit-exact vs JAX lowering) ----------------
#define TF_ROT(x0, x1, r) { x0 += x1; x1 = ((x1 << r) | (x1 >> (32 - r))); x1 ^= x0; }

__host__ __device__ __forceinline__ void threefry2x32(uint32_t k0, uint32_t k1,
                                                      uint32_t c0, uint32_t c1,
                                                      uint32_t& o0, uint32_t& o1) {
  uint32_t ks2 = k0 ^ k1 ^ 0x1BD11BDAu;
  uint32_t x0 = c0 + k0;
  uint32_t x1 = c1 + k1;
  TF_ROT(x0, x1, 13) TF_ROT(x0, x1, 15) TF_ROT(x0, x1, 26) TF_ROT(x0, x1, 6)
  x0 += k1;  x1 += ks2 + 1u;
  TF_ROT(x0, x1, 17) TF_ROT(x0, x1, 29) TF_ROT(x0, x1, 16) TF_ROT(x0, x1, 24)
  x0 += ks2; x1 += k0 + 2u;
  TF_ROT(x0, x1, 13) TF_ROT(x0, x1, 15) TF_ROT(x0, x1, 26) TF_ROT(x0, x1, 6)
  x0 += k0;  x1 += k1 + 3u;
  TF_ROT(x0, x1, 17) TF_ROT(x0, x1, 29) TF_ROT(x0, x1, 16) TF_ROT(x0, x1, 24)
  x0 += k1;  x1 += ks2 + 4u;
  TF_ROT(x0, x1, 13) TF_ROT(x0, x1, 15) TF_ROT(x0, x1, 26) TF_ROT(x0, x1, 6)
  x0 += ks2; x1 += k0 + 5u;
  o0 = x0; o1 = x1;
}

// Two independent chains, statements interleaved for explicit ILP-2.
// Returns bits = y0 ^ y1 (what JAX uniform consumes). c0 = 0 specialization.
#define TFR2(r) { xa0 += xa1; xb0 += xb1; \
                  xa1 = ((xa1 << r) | (xa1 >> (32 - r))) ^ xa0; \
                  xb1 = ((xb1 << r) | (xb1 >> (32 - r))) ^ xb0; }

__device__ __forceinline__ void threefry_x2(uint32_t k0, uint32_t k1,
                                            uint32_t ca, uint32_t cb,
                                            uint32_t& oa, uint32_t& ob) {
  const uint32_t ks2 = k0 ^ k1 ^ 0x1BD11BDAu;
  uint32_t xa0 = k0, xa1 = ca + k1;
  uint32_t xb0 = k0, xb1 = cb + k1;
  TFR2(13) TFR2(15) TFR2(26) TFR2(6)
  xa0 += k1;  xa1 += ks2 + 1u;  xb0 += k1;  xb1 += ks2 + 1u;
  TFR2(17) TFR2(29) TFR2(16) TFR2(24)
  xa0 += ks2; xa1 += k0 + 2u;   xb0 += ks2; xb1 += k0 + 2u;
  TFR2(13) TFR2(15) TFR2(26) TFR2(6)
  xa0 += k0;  xa1 += k1 + 3u;   xb0 += k0;  xb1 += k1 + 3u;
  TFR2(17) TFR2(29) TFR2(16) TFR2(24)
  xa0 += k1;  xa1 += ks2 + 4u;  xb0 += k1;  xb1 += ks2 + 4u;
  TFR2(13) TFR2(15) TFR2(26) TFR2(6)
  xa0 += ks2; xa1 += k0 + 5u;   xb0 += ks2; xb1 += k0 + 5u;
  oa = xa0 ^ xa1;
  ob = xb0 ^ xb1;
}

__device__ __forceinline__ uint16_t f2bf(float f) {  // RNE float->bf16
  uint32_t u = __float_as_uint(f);
  u += 0x7FFFu + ((u >> 16) & 1u);
  return (uint16_t)(u >> 16);
}

// ---------------- Kernel 1: FUSED prep + triplet mining ----------------
// Blocks [0,1024): sampling (VALU-bound long pole). Blocks [1024,2048): prep.
// __launch_bounds__(256,4): grid caps residency at 16 waves/CU anyway, so give
// the register allocator ~128 VGPRs to software-pipeline threefry chains.
__global__ __launch_bounds__(256, 4) void prep_sample_kernel(
    const float* __restrict__ F, uint8_t* __restrict__ Fq,
    float* __restrict__ norm2, float* __restrict__ sums, float* __restrict__ nv,
    const int* __restrict__ labels, int* __restrict__ pos_idx, int* __restrict__ neg_idx,
    uint32_t p0, uint32_t p1, uint32_t n0, uint32_t n1) {
  const int t = threadIdx.x;
  if (blockIdx.x >= SAMPLE_BLOCKS) {
    // ================= PREP branch: 4 rows/block, one wave per row =================
    const int w = t >> 6, l = t & 63;
    const int r = (blockIdx.x - SAMPLE_BLOCKS) * 4 + w;
    const float4* src = (const float4*)(F + (size_t)r * DIM);
    uint32_t* dst = (uint32_t*)(Fq + (size_t)r * DIM);
    float s = 0.f, q = 0.f;
#pragma unroll
    for (int c = 0; c < 4; ++c) {
      float4 v = src[c * 64 + l];
      s += (v.x + v.y) + (v.z + v.w);
      q += v.x * v.x + v.y * v.y + v.z * v.z + v.w * v.w;
      int wd = 0;
      wd = __builtin_amdgcn_cvt_pk_fp8_f32(v.x, v.y, wd, false);  // bytes 0,1
      wd = __builtin_amdgcn_cvt_pk_fp8_f32(v.z, v.w, wd, true);   // bytes 2,3
      dst[c * 64 + l] = (uint32_t)wd;
    }
    for (int off = 32; off; off >>= 1) { s += __shfl_xor(s, off); q += __shfl_xor(q, off); }
    if (l == 0) {
      norm2[r] = q; sums[r] = s;
      nv[r] = q + 2.0f * EPSV * s;
    }
    return;
  }
  // ================= SAMPLE branch: 4 rows/block =================
  __shared__ int plist[SROWS][64];
  __shared__ int pcnt[SROWS];
  __shared__ unsigned long long swp[SROWS];
  __shared__ unsigned long long swn[SROWS];
  const int i0 = blockIdx.x * SROWS;
  if (t < SROWS) { pcnt[t] = 0; swp[t] = 0ull; swn[t] = 0ull; }
  int lj[16];
#pragma unroll
  for (int c = 0; c < 16; ++c) lj[c] = labels[c * 256 + t];
  __syncthreads();
  const int lane = t & 63;
#pragma unroll 1  // keep body ~10 KB (16 inlined threefry chains) — I$ is 32 KB
  for (int r = 0; r < SROWS; ++r) {
    const int li = labels[i0 + r];  // block-uniform -> scalar load
    const uint32_t base = (uint32_t)(i0 + r) * (uint32_t)BSZ + (uint32_t)t;
    uint32_t bestn = 0u;
    // HOT LOOP: branch-free (cndmask only) so the 8 independent x2-chains
    // software-pipeline; candidate push deferred to a re-compare loop below.
#pragma unroll
    for (int c = 0; c < 16; c += 2) {
      uint32_t bitsA, bitsB;
      threefry_x2(n0, n1, base + (uint32_t)(c * 256), base + (uint32_t)((c + 1) * 256),
                  bitsA, bitsB);
      // ((y>>9)<<4)|(15-c) == ((y>>5)&~15)|(15-c) -> v_and_or_b32
      const uint32_t packA = ((bitsA >> 5) & 0xFFFFFFF0u) | (uint32_t)(15 - c);
      const uint32_t packB = ((bitsB >> 5) & 0xFFFFFFF0u) | (uint32_t)(14 - c);
      const uint32_t vA = (lj[c] == li) ? 0u : packA;
      const uint32_t vB = (lj[c + 1] == li) ? 0u : packB;
      const uint32_t m = vA > vB ? vA : vB;  // low-4-bit tags differ: no cross-c tie
      if (m > bestn) bestn = m;
    }
    // lane-local 32-bit -> global 64-bit key (tie -> lower j, matching JAX argmax)
    unsigned long long keyn = 0ull;
    if (bestn) {
      const int c = 15 - (int)(bestn & 15u);
      const int j = c * 256 + t;
      keyn = ((unsigned long long)(bestn >> 4) << 32) | (uint32_t)(~j);
    }
    for (int off = 32; off; off >>= 1) {
      unsigned long long o = __shfl_xor(keyn, off);
      if (o > keyn) keyn = o;
    }
    if (lane == 0) atomicMax(&swn[r], keyn);
    // Candidate push (re-compare): ~16 VALU + rare divergent push, outside hot loop
#pragma unroll
    for (int c = 0; c < 16; ++c) {
      if (lj[c] == li) {
        int sl = atomicAdd(&pcnt[r], 1);
        if (sl < 64) plist[r][sl] = c * 256 + t;
      }
    }
  }
  __syncthreads();  // fences plist/pcnt/swn
  // POS phase: wave w handles row w's candidate list (~8 entries)
  const int w = t >> 6;
  {
    const int cnt = pcnt[w] < 64 ? pcnt[w] : 64;
    if (lane < cnt) {
      const int j = plist[w][lane];
      uint32_t y0, y1;
      threefry2x32(p0, p1, 0u, (uint32_t)(i0 + w) * (uint32_t)BSZ + (uint32_t)j, y0, y1);
      const unsigned long long key =
          ((unsigned long long)((y0 ^ y1) >> 9) << 32) | (uint32_t)(~j);
      atomicMax(&swp[w], key);
    }
  }
  __syncthreads();
  if (t < SROWS) {
    pos_idx[i0 + t] = (int)(~(uint32_t)swp[t]);  // i itself always matches -> swp != 0
    const unsigned long long vn = swn[t];
    neg_idx[i0 + t] = (vn == 0ull) ? 0 : (int)(~(uint32_t)vn);
  }
}

// ---------------- Kernel 2: G = Fq * Fq^T, fp8 MX K=128, triangle, bf16 out ----------------
using int8v = __attribute__((ext_vector_type(8))) int;
using int4v = __attribute__((ext_vector_type(4))) int;
using f32x4 = __attribute__((ext_vector_type(4))) float;

__device__ __forceinline__ void async_load16(const void* g, void* l) {
  __builtin_amdgcn_global_load_lds((__attribute__((address_space(1))) void*)g,
                                   (__attribute__((address_space(3))) void*)l, 16, 0, 0);
}

// LDS layout: row r (128 B) holds 8 chunks of 16 B; chunk c stored at slot c ^ (r & 7).
__global__ __launch_bounds__(256) void gemm_kernel(const uint8_t* __restrict__ Fq,
                                                   uint16_t* __restrict__ Gb) {
  // Triangular block decode: p = by*(by+1)/2 + bx, bx <= by  (32x32 block grid)
  const int p = blockIdx.x;
  int by = (int)((sqrtf(8.0f * (float)p + 1.0f) - 1.0f) * 0.5f);
  if ((by + 1) * (by + 2) / 2 <= p) ++by;
  if (by * (by + 1) / 2 > p) --by;
  const int bx = p - by * (by + 1) / 2;

  __shared__ __align__(16) uint8_t lA[128 * 128];  // 16 KB
  __shared__ __align__(16) uint8_t lB[128 * 128];
  const int t = threadIdx.x;
  const int l = t & 63;
  const int w = t >> 6;
  const int wm = (w >> 1) * 64;
  const int wn = (w & 1) * 64;
  const int bm = bx * 128;
  const int bn = by * 128;

  f32x4 acc[4][4] = {};

  const int srow = t >> 3;  // 0..31
  const int scol = (((t & 7) ^ ((t >> 3) & 7)) << 4);  // XOR-swizzled source chunk
  const uint8_t* gA0 = Fq + (size_t)(bm + srow) * DIM + scol;
  const uint8_t* gB0 = Fq + (size_t)(bn + srow) * DIM + scol;

  // Fragment LDS byte offsets (iteration-invariant): row fra, chunks c0, c0+1
  const int fr = l & 15;
  const int c0 = (l >> 4) * 2;
  int offA[4][2], offB[4][2];
#pragma unroll
  for (int tm = 0; tm < 4; ++tm) {
    const int fra = wm + tm * 16 + fr, sw = fra & 7;
    offA[tm][0] = fra * 128 + ((c0 ^ sw) << 4);
    offA[tm][1] = fra * 128 + (((c0 + 1) ^ sw) << 4);
    const int frb = wn + tm * 16 + fr, sb = frb & 7;
    offB[tm][0] = frb * 128 + ((c0 ^ sb) << 4);
    offB[tm][1] = frb * 128 + (((c0 + 1) ^ sb) << 4);
  }

  for (int it = 0; it < 8; ++it) {  // K = 1024, BK = 128
    const int k0 = it * 128;
    __syncthreads();
#pragma unroll
    for (int ld = 0; ld < 4; ++ld) {
      async_load16(gA0 + (size_t)ld * 32 * DIM + k0, (char*)lA + (ld * 256 + t) * 16);
      async_load16(gB0 + (size_t)ld * 32 * DIM + k0, (char*)lB + (ld * 256 + t) * 16);
    }
    __syncthreads();
    int8v av[4], bv[4];
#pragma unroll
    for (int tm = 0; tm < 4; ++tm) {
      int4v alo = *(const int4v*)&lA[offA[tm][0]];
      int4v ahi = *(const int4v*)&lA[offA[tm][1]];
      av[tm] = __builtin_shufflevector(alo, ahi, 0, 1, 2, 3, 4, 5, 6, 7);
      int4v blo = *(const int4v*)&lB[offB[tm][0]];
      int4v bhi = *(const int4v*)&lB[offB[tm][1]];
      bv[tm] = __builtin_shufflevector(blo, bhi, 0, 1, 2, 3, 4, 5, 6, 7);
    }
#pragma unroll
    for (int tm = 0; tm < 4; ++tm)
#pragma unroll
      for (int tn = 0; tn < 4; ++tn)
        acc[tm][tn] = __builtin_amdgcn_mfma_scale_f32_16x16x128_f8f6f4(
            av[tm], bv[tn], acc[tm][tn],
            0, 0,                       // cbsz/blgp = fp8 e4m3
            0, 0x7F7F7F7F,              // scale A = 1.0 (E8M0 127)
            0, 0x7F7F7F7F);             // scale B = 1.0
  }
  // C/D layout: col = lane&15, row = (lane>>4)*4 + reg
  const int cr = (l >> 4) * 4;
  const int cc = l & 15;
#pragma unroll
  for (int tm = 0; tm < 4; ++tm)
#pragma unroll
    for (int tn = 0; tn < 4; ++tn) {
      const int row0 = bm + wm + tm * 16 + cr;
      const int col  = bn + wn + tn * 16 + cc;
      ushort h0 = f2bf(acc[tm][tn][0]), h1 = f2bf(acc[tm][tn][1]);
      ushort h2 = f2bf(acc[tm][tn][2]), h3 = f2bf(acc[tm][tn][3]);
      Gb[(size_t)(row0 + 0) * BSZ + col] = h0;
      Gb[(size_t)(row0 + 1) * BSZ + col] = h1;
      Gb[(size_t)(row0 + 2) * BSZ + col] = h2;
      Gb[(size_t)(row0 + 3) * BSZ + col] = h3;
      // Mirror tile (G symmetric): 4 consecutive rows -> contiguous ushort4 (8 B)
      ushort4 v = make_ushort4(h0, h1, h2, h3);
      *(ushort4*)&Gb[(size_t)col * BSZ + row0] = v;
    }
}

// ---------------- Kernel 3: loss, 1 row/block, plain partial store ----------------
__device__ __forceinline__ float bfl(uint32_t w) { return __uint_as_float(w << 16); }
__device__ __forceinline__ float bfh(uint32_t w) { return __uint_as_float(w & 0xFFFF0000u); }

__global__ __launch_bounds__(256) void loss_kernel(const uint16_t* __restrict__ Gb,
                                                   const float* __restrict__ norm2,
                                                   const float* __restrict__ sums,
                                                   const float* __restrict__ nv,
                                                   const int* __restrict__ pos_idx,
                                                   const int* __restrict__ neg_idx,
                                                   float* __restrict__ partial) {
  const int i = blockIdx.x, t = threadIdx.x;
  const int a = pos_idx[i], b = neg_idx[i];
  const float deps2 = (float)DIM * EPSV * EPSV;
  const float ca = norm2[a] - 2.0f * EPSV * sums[a] + deps2;
  const float cb = norm2[b] - 2.0f * EPSV * sums[b] + deps2;
  const uint4* Ga = (const uint4*)(Gb + (size_t)a * BSZ);
  const uint4* Gn = (const uint4*)(Gb + (size_t)b * BSZ);
  const float4* N4 = (const float4*)nv;
  // 16 entries per thread, all loads independent & coalesced (32 B/lane)
  uint4 ga[2], gn[2];
  float4 njv[4];
  ga[0] = Ga[t * 2]; ga[1] = Ga[t * 2 + 1];
  gn[0] = Gn[t * 2]; gn[1] = Gn[t * 2 + 1];
#pragma unroll
  for (int k = 0; k < 4; ++k) njv[k] = N4[t * 4 + k];
  float s = 0.f;
#pragma unroll
  for (int h = 0; h < 2; ++h) {
    const uint4 gau = ga[h], gnu = gn[h];
    float gav[8] = {bfl(gau.x), bfh(gau.x), bfl(gau.y), bfh(gau.y),
                    bfl(gau.z), bfh(gau.z), bfl(gau.w), bfh(gau.w)};
    float gnv[8] = {bfl(gnu.x), bfh(gnu.x), bfl(gnu.y), bfh(gnu.y),
                    bfl(gnu.z), bfh(gnu.z), bfl(gnu.w), bfh(gnu.w)};
    const float4 na = njv[h * 2], nb = njv[h * 2 + 1];
    float nj[8] = {na.x, na.y, na.z, na.w, nb.x, nb.y, nb.z, nb.w};
#pragma unroll
    for (int e = 0; e < 8; ++e) {
      const float dap = sqrtf(fmaxf(fmaf(-2.f, gav[e], nj[e] + ca), 1e-12f));
      const float dan = sqrtf(fmaxf(fmaf(-2.f, gnv[e], nj[e] + cb), 1e-12f));
      s += fmaxf(dap - dan + MARGINV, 0.f);
    }
  }
  for (int off = 32; off; off >>= 1) s += __shfl_xor(s, off);
  __shared__ float ps[4];
  const int w = t >> 6, lane = t & 63;
  if (lane == 0) ps[w] = s;
  __syncthreads();
  if (t == 0) partial[i] = (ps[0] + ps[1]) + (ps[2] + ps[3]);  // plain store; the
  // kernel boundary (stream order) publishes it to finalize — no fence/ticket
  // (R6 lesson: per-block agent-scope tickets serialize at ~50 ns each).
}

// ---------------- Kernel 4: finalize (1 block) ----------------
__global__ __launch_bounds__(256) void finalize_kernel(const float* __restrict__ partial,
                                                       float* __restrict__ out) {
  const int t = threadIdx.x;
  const float4* P4 = (const float4*)partial;
  float s = 0.f;
#pragma unroll
  for (int k = 0; k < 4; ++k) {  // 4096 partials = 1024 float4
    float4 v = P4[k * 256 + t];
    s += (v.x + v.y) + (v.z + v.w);
  }
  for (int off = 32; off; off >>= 1) s += __shfl_xor(s, off);
  __shared__ float ps[4];
  const int w = t >> 6, lane = t & 63;
  if (lane == 0) ps[w] = s;
  __syncthreads();
  if (t == 0)
    out[0] = ((ps[0] + ps[1]) + (ps[2] + ps[3])) * (1.0f / ((float)BSZ * (float)BSZ));
}

// ---------------- Launch ----------------
extern "C" void kernel_launch(void* const* d_in, const int* in_sizes, int n_in,
                              void* d_out, int out_size, void* d_ws, size_t ws_size,
                              hipStream_t stream) {
  const float* feat = (const float*)d_in[0];
  const int* labels = (const int*)d_in[1];
  float* out = (float*)d_out;

  char* ws = (char*)d_ws;
  uint16_t* Gb     = (uint16_t*)ws;                               // 32 MB (bf16 G)
  uint8_t* Fq      = (uint8_t*)(ws + (size_t)33554432);           // 4 MB
  float* norm2     = (float*)(ws + (size_t)37748736);             // 16 KB
  float* sums      = (float*)(ws + (size_t)37748736 + 16384);     // 16 KB
  float* nv        = (float*)(ws + (size_t)37748736 + 32768);     // 16 KB
  int* pos_idx     = (int*)  (ws + (size_t)37748736 + 49152);     // 16 KB
  int* neg_idx     = (int*)  (ws + (size_t)37748736 + 65536);     // 16 KB
  float* partial   = (float*)(ws + (size_t)37748736 + 81920);     // 16 KB

  // JAX partitionable split: k_i = threefry(base_key=(0,42), (0, i))
  uint32_t k1a, k1b, k2a, k2b;
  threefry2x32(0u, 42u, 0u, 0u, k1a, k1b);  // k1 -> pos uniforms
  threefry2x32(0u, 42u, 0u, 1u, k2a, k2b);  // k2 -> neg uniforms

  prep_sample_kernel<<<dim3(SAMPLE_BLOCKS + PREP_BLOCKS), dim3(256), 0, stream>>>(
      feat, Fq, norm2, sums, nv, labels, pos_idx, neg_idx, k1a, k1b, k2a, k2b);
  gemm_kernel<<<dim3(528), dim3(256), 0, stream>>>(Fq, Gb);
  loss_kernel<<<dim3(BSZ), dim3(256), 0, stream>>>(Gb, norm2, sums, nv, pos_idx,
                                                   neg_idx, partial);
  finalize_kernel<<<dim3(1), dim3(256), 0, stream>>>(partial, out);
}

// Round 10
// 136.614 us; speedup vs baseline: 2.4060x; 1.0471x over previous
//
#include <hip/hip_runtime.h>
#include <stdint.h>

// Problem constants (B=4096, D=1024 from setup_inputs)
#define BSZ 4096
#define DIM 1024
#define EPSV 1e-6f
#define MARGINV 0.3f
#define SROWS 4
#define GEMM_BLOCKS 528               // triangle of 32x32 block grid, blockIdx [0,528)
#define SAMPLE_BLOCKS (BSZ / SROWS)   // 1024, blockIdx [528, 1552)

// ---------------- Threefry-2x32 (bit-exact vs JAX lowering) ----------------
#define TF_ROT(x0, x1, r) { x0 += x1; x1 = ((x1 << r) | (x1 >> (32 - r))); x1 ^= x0; }

__host__ __device__ __forceinline__ void threefry2x32(uint32_t k0, uint32_t k1,
                                                      uint32_t c0, uint32_t c1,
                                                      uint32_t& o0, uint32_t& o1) {
  uint32_t ks2 = k0 ^ k1 ^ 0x1BD11BDAu;
  uint32_t x0 = c0 + k0;
  uint32_t x1 = c1 + k1;
  TF_ROT(x0, x1, 13) TF_ROT(x0, x1, 15) TF_ROT(x0, x1, 26) TF_ROT(x0, x1, 6)
  x0 += k1;  x1 += ks2 + 1u;
  TF_ROT(x0, x1, 17) TF_ROT(x0, x1, 29) TF_ROT(x0, x1, 16) TF_ROT(x0, x1, 24)
  x0 += ks2; x1 += k0 + 2u;
  TF_ROT(x0, x1, 13) TF_ROT(x0, x1, 15) TF_ROT(x0, x1, 26) TF_ROT(x0, x1, 6)
  x0 += k0;  x1 += k1 + 3u;
  TF_ROT(x0, x1, 17) TF_ROT(x0, x1, 29) TF_ROT(x0, x1, 16) TF_ROT(x0, x1, 24)
  x0 += k1;  x1 += ks2 + 4u;
  TF_ROT(x0, x1, 13) TF_ROT(x0, x1, 15) TF_ROT(x0, x1, 26) TF_ROT(x0, x1, 6)
  x0 += ks2; x1 += k0 + 5u;
  o0 = x0; o1 = x1;
}

// Two independent chains, statements interleaved for explicit ILP-2.
#define TFR2(r) { xa0 += xa1; xb0 += xb1; \
                  xa1 = ((xa1 << r) | (xa1 >> (32 - r))) ^ xa0; \
                  xb1 = ((xb1 << r) | (xb1 >> (32 - r))) ^ xb0; }

__device__ __forceinline__ void threefry_x2(uint32_t k0, uint32_t k1,
                                            uint32_t ca, uint32_t cb,
                                            uint32_t& oa, uint32_t& ob) {
  const uint32_t ks2 = k0 ^ k1 ^ 0x1BD11BDAu;
  uint32_t xa0 = k0, xa1 = ca + k1;
  uint32_t xb0 = k0, xb1 = cb + k1;
  TFR2(13) TFR2(15) TFR2(26) TFR2(6)
  xa0 += k1;  xa1 += ks2 + 1u;  xb0 += k1;  xb1 += ks2 + 1u;
  TFR2(17) TFR2(29) TFR2(16) TFR2(24)
  xa0 += ks2; xa1 += k0 + 2u;   xb0 += ks2; xb1 += k0 + 2u;
  TFR2(13) TFR2(15) TFR2(26) TFR2(6)
  xa0 += k0;  xa1 += k1 + 3u;   xb0 += k0;  xb1 += k1 + 3u;
  TFR2(17) TFR2(29) TFR2(16) TFR2(24)
  xa0 += k1;  xa1 += ks2 + 4u;  xb0 += k1;  xb1 += ks2 + 4u;
  TFR2(13) TFR2(15) TFR2(26) TFR2(6)
  xa0 += ks2; xa1 += k0 + 5u;   xb0 += ks2; xb1 += k0 + 5u;
  oa = xa0 ^ xa1;
  ob = xb0 ^ xb1;
}

__device__ __forceinline__ uint16_t f2bf(float f) {  // RNE float->bf16
  uint32_t u = __float_as_uint(f);
  u += 0x7FFFu + ((u >> 16) & 1u);
  return (uint16_t)(u >> 16);
}

// ---------------- Kernel 1: norms/sums/nv + fp8 convert (must precede gemm) ----------------
__global__ __launch_bounds__(256) void prep_kernel(const float* __restrict__ F,
                                                   uint8_t* __restrict__ Fq,
                                                   float* __restrict__ norm2,
                                                   float* __restrict__ sums,
                                                   float* __restrict__ nv) {
  const int w = threadIdx.x >> 6, l = threadIdx.x & 63;
  const int r = blockIdx.x * 4 + w;  // one wave per row
  const float4* src = (const float4*)(F + (size_t)r * DIM);
  uint32_t* dst = (uint32_t*)(Fq + (size_t)r * DIM);
  float s = 0.f, q = 0.f;
#pragma unroll
  for (int c = 0; c < 4; ++c) {
    float4 v = src[c * 64 + l];
    s += (v.x + v.y) + (v.z + v.w);
    q += v.x * v.x + v.y * v.y + v.z * v.z + v.w * v.w;
    int wd = 0;
    wd = __builtin_amdgcn_cvt_pk_fp8_f32(v.x, v.y, wd, false);  // bytes 0,1
    wd = __builtin_amdgcn_cvt_pk_fp8_f32(v.z, v.w, wd, true);   // bytes 2,3
    dst[c * 64 + l] = (uint32_t)wd;
  }
  for (int off = 32; off; off >>= 1) { s += __shfl_xor(s, off); q += __shfl_xor(q, off); }
  if (l == 0) {
    norm2[r] = q; sums[r] = s;
    nv[r] = q + 2.0f * EPSV * s;
  }
}

// ---------------- Kernel 2: FUSED gemm + sample ----------------
// GEMM blocks FIRST (blockIdx 0..527): all resident immediately (MFMA/VMEM-bound),
// sample blocks (VALU-bound) fill remaining CU slots -> m114-style pipe overlap.
using int8v = __attribute__((ext_vector_type(8))) int;
using int4v = __attribute__((ext_vector_type(4))) int;
using f32x4 = __attribute__((ext_vector_type(4))) float;

__device__ __forceinline__ void async_load16(const void* g, void* l) {
  __builtin_amdgcn_global_load_lds((__attribute__((address_space(1))) void*)g,
                                   (__attribute__((address_space(3))) void*)l, 16, 0, 0);
}

__global__ __launch_bounds__(256, 4) void gemm_sample_kernel(
    const uint8_t* __restrict__ Fq, uint16_t* __restrict__ Gb,
    const int* __restrict__ labels, int* __restrict__ pos_idx, int* __restrict__ neg_idx,
    uint32_t p0, uint32_t p1, uint32_t n0, uint32_t n1) {
  // Shared union: gemm staging (32 KB) / sample lists (~2.2 KB)
  __shared__ __align__(16) uint8_t lA[128 * 128];
  __shared__ __align__(16) uint8_t lB[128 * 128];
  const int t = threadIdx.x;

  if (blockIdx.x >= GEMM_BLOCKS) {
    // ================= SAMPLE branch: 4 rows/block =================
    int* plist = (int*)lA;                                   // [SROWS][64]
    int* pcnt = (int*)(lA + SROWS * 64 * 4);                 // [SROWS]
    unsigned long long* swp = (unsigned long long*)(lB);     // [SROWS]
    unsigned long long* swn = (unsigned long long*)(lB + 64);// [SROWS]
    const int i0 = (blockIdx.x - GEMM_BLOCKS) * SROWS;
    if (t < SROWS) { pcnt[t] = 0; swp[t] = 0ull; swn[t] = 0ull; }
    int lj[16];
#pragma unroll
    for (int c = 0; c < 16; ++c) lj[c] = labels[c * 256 + t];
    __syncthreads();
    const int lane = t & 63;
#pragma unroll 1  // keep body compact (16 inlined threefry chains) — I$ is 32 KB
    for (int r = 0; r < SROWS; ++r) {
      const int li = labels[i0 + r];  // block-uniform -> scalar load
      const uint32_t base = (uint32_t)(i0 + r) * (uint32_t)BSZ + (uint32_t)t;
      uint32_t bestn = 0u;
      // Branch-free hot loop; candidate push deferred to re-compare below.
#pragma unroll
      for (int c = 0; c < 16; c += 2) {
        uint32_t bitsA, bitsB;
        threefry_x2(n0, n1, base + (uint32_t)(c * 256), base + (uint32_t)((c + 1) * 256),
                    bitsA, bitsB);
        const uint32_t packA = ((bitsA >> 5) & 0xFFFFFFF0u) | (uint32_t)(15 - c);
        const uint32_t packB = ((bitsB >> 5) & 0xFFFFFFF0u) | (uint32_t)(14 - c);
        const uint32_t vA = (lj[c] == li) ? 0u : packA;
        const uint32_t vB = (lj[c + 1] == li) ? 0u : packB;
        const uint32_t m = vA > vB ? vA : vB;  // low-4-bit tags differ: no cross-c tie
        if (m > bestn) bestn = m;
      }
      // lane-local 32-bit -> global 64-bit key (tie -> lower j, matching JAX argmax)
      unsigned long long keyn = 0ull;
      if (bestn) {
        const int c = 15 - (int)(bestn & 15u);
        const int j = c * 256 + t;
        keyn = ((unsigned long long)(bestn >> 4) << 32) | (uint32_t)(~j);
      }
      for (int off = 32; off; off >>= 1) {
        unsigned long long o = __shfl_xor(keyn, off);
        if (o > keyn) keyn = o;
      }
      if (lane == 0) atomicMax(&swn[r], keyn);
      // Candidate push (re-compare): rare divergence outside the hot loop
#pragma unroll
      for (int c = 0; c < 16; ++c) {
        if (lj[c] == li) {
          int sl = atomicAdd(&pcnt[r], 1);
          if (sl < 64) plist[r * 64 + sl] = c * 256 + t;
        }
      }
    }
    __syncthreads();  // fences plist/pcnt/swn
    // POS phase: wave w handles row w's candidate list (~8 entries)
    const int w = t >> 6;
    {
      const int cnt = pcnt[w] < 64 ? pcnt[w] : 64;
      if (lane < cnt) {
        const int j = plist[w * 64 + lane];
        uint32_t y0, y1;
        threefry2x32(p0, p1, 0u, (uint32_t)(i0 + w) * (uint32_t)BSZ + (uint32_t)j, y0, y1);
        const unsigned long long key =
            ((unsigned long long)((y0 ^ y1) >> 9) << 32) | (uint32_t)(~j);
        atomicMax(&swp[w], key);
      }
    }
    __syncthreads();
    if (t < SROWS) {
      pos_idx[i0 + t] = (int)(~(uint32_t)swp[t]);  // i itself always matches -> swp != 0
      const unsigned long long vn = swn[t];
      neg_idx[i0 + t] = (vn == 0ull) ? 0 : (int)(~(uint32_t)vn);
    }
    return;
  }

  // ================= GEMM branch: fp8 MX K=128, triangle, bf16 out =================
  // Triangular block decode: p = by*(by+1)/2 + bx, bx <= by  (32x32 block grid)
  const int p = blockIdx.x;
  int by = (int)((sqrtf(8.0f * (float)p + 1.0f) - 1.0f) * 0.5f);
  if ((by + 1) * (by + 2) / 2 <= p) ++by;
  if (by * (by + 1) / 2 > p) --by;
  const int bx = p - by * (by + 1) / 2;

  const int l = t & 63;
  const int w = t >> 6;
  const int wm = (w >> 1) * 64;
  const int wn = (w & 1) * 64;
  const int bm = bx * 128;
  const int bn = by * 128;

  f32x4 acc[4][4] = {};

  const int srow = t >> 3;  // 0..31
  const int scol = (((t & 7) ^ ((t >> 3) & 7)) << 4);  // XOR-swizzled source chunk
  const uint8_t* gA0 = Fq + (size_t)(bm + srow) * DIM + scol;
  const uint8_t* gB0 = Fq + (size_t)(bn + srow) * DIM + scol;

  // Fragment LDS byte offsets (iteration-invariant): row fra, chunks c0, c0+1
  const int fr = l & 15;
  const int c0 = (l >> 4) * 2;
  int offA[4][2], offB[4][2];
#pragma unroll
  for (int tm = 0; tm < 4; ++tm) {
    const int fra = wm + tm * 16 + fr, sw = fra & 7;
    offA[tm][0] = fra * 128 + ((c0 ^ sw) << 4);
    offA[tm][1] = fra * 128 + (((c0 + 1) ^ sw) << 4);
    const int frb = wn + tm * 16 + fr, sb = frb & 7;
    offB[tm][0] = frb * 128 + ((c0 ^ sb) << 4);
    offB[tm][1] = frb * 128 + (((c0 + 1) ^ sb) << 4);
  }

  for (int it = 0; it < 8; ++it) {  // K = 1024, BK = 128
    const int k0 = it * 128;
    __syncthreads();
#pragma unroll
    for (int ld = 0; ld < 4; ++ld) {
      async_load16(gA0 + (size_t)ld * 32 * DIM + k0, (char*)lA + (ld * 256 + t) * 16);
      async_load16(gB0 + (size_t)ld * 32 * DIM + k0, (char*)lB + (ld * 256 + t) * 16);
    }
    __syncthreads();
    int8v av[4], bv[4];
#pragma unroll
    for (int tm = 0; tm < 4; ++tm) {
      int4v alo = *(const int4v*)&lA[offA[tm][0]];
      int4v ahi = *(const int4v*)&lA[offA[tm][1]];
      av[tm] = __builtin_shufflevector(alo, ahi, 0, 1, 2, 3, 4, 5, 6, 7);
      int4v blo = *(const int4v*)&lB[offB[tm][0]];
      int4v bhi = *(const int4v*)&lB[offB[tm][1]];
      bv[tm] = __builtin_shufflevector(blo, bhi, 0, 1, 2, 3, 4, 5, 6, 7);
    }
#pragma unroll
    for (int tm = 0; tm < 4; ++tm)
#pragma unroll
      for (int tn = 0; tn < 4; ++tn)
        acc[tm][tn] = __builtin_amdgcn_mfma_scale_f32_16x16x128_f8f6f4(
            av[tm], bv[tn], acc[tm][tn],
            0, 0,                       // cbsz/blgp = fp8 e4m3
            0, 0x7F7F7F7F,              // scale A = 1.0 (E8M0 127)
            0, 0x7F7F7F7F);             // scale B = 1.0
  }
  // C/D layout: col = lane&15, row = (lane>>4)*4 + reg
  const int cr = (l >> 4) * 4;
  const int cc = l & 15;
#pragma unroll
  for (int tm = 0; tm < 4; ++tm)
#pragma unroll
    for (int tn = 0; tn < 4; ++tn) {
      const int row0 = bm + wm + tm * 16 + cr;
      const int col  = bn + wn + tn * 16 + cc;
      ushort h0 = f2bf(acc[tm][tn][0]), h1 = f2bf(acc[tm][tn][1]);
      ushort h2 = f2bf(acc[tm][tn][2]), h3 = f2bf(acc[tm][tn][3]);
      Gb[(size_t)(row0 + 0) * BSZ + col] = h0;
      Gb[(size_t)(row0 + 1) * BSZ + col] = h1;
      Gb[(size_t)(row0 + 2) * BSZ + col] = h2;
      Gb[(size_t)(row0 + 3) * BSZ + col] = h3;
      // Mirror tile (G symmetric): 4 consecutive rows -> contiguous ushort4 (8 B)
      ushort4 v = make_ushort4(h0, h1, h2, h3);
      *(ushort4*)&Gb[(size_t)col * BSZ + row0] = v;
    }
}

// ---------------- Kernel 3: loss, 1 row/block, plain partial store ----------------
__device__ __forceinline__ float bfl(uint32_t w) { return __uint_as_float(w << 16); }
__device__ __forceinline__ float bfh(uint32_t w) { return __uint_as_float(w & 0xFFFF0000u); }

__global__ __launch_bounds__(256) void loss_kernel(const uint16_t* __restrict__ Gb,
                                                   const float* __restrict__ norm2,
                                                   const float* __restrict__ sums,
                                                   const float* __restrict__ nv,
                                                   const int* __restrict__ pos_idx,
                                                   const int* __restrict__ neg_idx,
                                                   float* __restrict__ partial) {
  const int i = blockIdx.x, t = threadIdx.x;
  const int a = pos_idx[i], b = neg_idx[i];
  const float deps2 = (float)DIM * EPSV * EPSV;
  const float ca = norm2[a] - 2.0f * EPSV * sums[a] + deps2;
  const float cb = norm2[b] - 2.0f * EPSV * sums[b] + deps2;
  const uint4* Ga = (const uint4*)(Gb + (size_t)a * BSZ);
  const uint4* Gn = (const uint4*)(Gb + (size_t)b * BSZ);
  const float4* N4 = (const float4*)nv;
  // 16 entries per thread, all loads independent & coalesced (32 B/lane)
  uint4 ga[2], gn[2];
  float4 njv[4];
  ga[0] = Ga[t * 2]; ga[1] = Ga[t * 2 + 1];
  gn[0] = Gn[t * 2]; gn[1] = Gn[t * 2 + 1];
#pragma unroll
  for (int k = 0; k < 4; ++k) njv[k] = N4[t * 4 + k];
  float s = 0.f;
#pragma unroll
  for (int h = 0; h < 2; ++h) {
    const uint4 gau = ga[h], gnu = gn[h];
    float gav[8] = {bfl(gau.x), bfh(gau.x), bfl(gau.y), bfh(gau.y),
                    bfl(gau.z), bfh(gau.z), bfl(gau.w), bfh(gau.w)};
    float gnv[8] = {bfl(gnu.x), bfh(gnu.x), bfl(gnu.y), bfh(gnu.y),
                    bfl(gnu.z), bfh(gnu.z), bfl(gnu.w), bfh(gnu.w)};
    const float4 na = njv[h * 2], nb = njv[h * 2 + 1];
    float nj[8] = {na.x, na.y, na.z, na.w, nb.x, nb.y, nb.z, nb.w};
#pragma unroll
    for (int e = 0; e < 8; ++e) {
      const float dap = sqrtf(fmaxf(fmaf(-2.f, gav[e], nj[e] + ca), 1e-12f));
      const float dan = sqrtf(fmaxf(fmaf(-2.f, gnv[e], nj[e] + cb), 1e-12f));
      s += fmaxf(dap - dan + MARGINV, 0.f);
    }
  }
  for (int off = 32; off; off >>= 1) s += __shfl_xor(s, off);
  __shared__ float ps[4];
  const int w = t >> 6, lane = t & 63;
  if (lane == 0) ps[w] = s;
  __syncthreads();
  if (t == 0) partial[i] = (ps[0] + ps[1]) + (ps[2] + ps[3]);  // plain store; the
  // kernel boundary (stream order) publishes it to finalize — no fence/ticket
  // (R6 lesson: per-block agent-scope tickets serialize at ~50 ns each).
}

// ---------------- Kernel 4: finalize (1 block) ----------------
__global__ __launch_bounds__(256) void finalize_kernel(const float* __restrict__ partial,
                                                       float* __restrict__ out) {
  const int t = threadIdx.x;
  const float4* P4 = (const float4*)partial;
  float s = 0.f;
#pragma unroll
  for (int k = 0; k < 4; ++k) {  // 4096 partials = 1024 float4
    float4 v = P4[k * 256 + t];
    s += (v.x + v.y) + (v.z + v.w);
  }
  for (int off = 32; off; off >>= 1) s += __shfl_xor(s, off);
  __shared__ float ps[4];
  const int w = t >> 6, lane = t & 63;
  if (lane == 0) ps[w] = s;
  __syncthreads();
  if (t == 0)
    out[0] = ((ps[0] + ps[1]) + (ps[2] + ps[3])) * (1.0f / ((float)BSZ * (float)BSZ));
}

// ---------------- Launch ----------------
extern "C" void kernel_launch(void* const* d_in, const int* in_sizes, int n_in,
                              void* d_out, int out_size, void* d_ws, size_t ws_size,
                              hipStream_t stream) {
  const float* feat = (const float*)d_in[0];
  const int* labels = (const int*)d_in[1];
  float* out = (float*)d_out;

  char* ws = (char*)d_ws;
  uint16_t* Gb     = (uint16_t*)ws;                               // 32 MB (bf16 G)
  uint8_t* Fq      = (uint8_t*)(ws + (size_t)33554432);           // 4 MB
  float* norm2     = (float*)(ws + (size_t)37748736);             // 16 KB
  float* sums      = (float*)(ws + (size_t)37748736 + 16384);     // 16 KB
  float* nv        = (float*)(ws + (size_t)37748736 + 32768);     // 16 KB
  int* pos_idx     = (int*)  (ws + (size_t)37748736 + 49152);     // 16 KB
  int* neg_idx     = (int*)  (ws + (size_t)37748736 + 65536);     // 16 KB
  float* partial   = (float*)(ws + (size_t)37748736 + 81920);     // 16 KB

  // JAX partitionable split: k_i = threefry(base_key=(0,42), (0, i))
  uint32_t k1a, k1b, k2a, k2b;
  threefry2x32(0u, 42u, 0u, 0u, k1a, k1b);  // k1 -> pos uniforms
  threefry2x32(0u, 42u, 0u, 1u, k2a, k2b);  // k2 -> neg uniforms

  prep_kernel<<<dim3(BSZ / 4), dim3(256), 0, stream>>>(feat, Fq, norm2, sums, nv);
  gemm_sample_kernel<<<dim3(GEMM_BLOCKS + SAMPLE_BLOCKS), dim3(256), 0, stream>>>(
      Fq, Gb, labels, pos_idx, neg_idx, k1a, k1b, k2a, k2b);
  loss_kernel<<<dim3(BSZ), dim3(256), 0, stream>>>(Gb, norm2, sums, nv, pos_idx,
                                                   neg_idx, partial);
  finalize_kernel<<<dim3(1), dim3(256), 0, stream>>>(partial, out);
}